// Round 3
// baseline (1941.852 us; speedup 1.0000x reference)
//
#include <hip/hip_runtime.h>
#include <math.h>

static constexpr int F  = 128;    // channels per head
static constexpr int H  = 4;      // heads
static constexpr int HF = 512;    // H*F
static constexpr int NC = 1664;   // packed GEMM cols: Q(512)|K(512)|V(512)|S(128)
static constexpr int LAYERS = 4;

typedef __attribute__((ext_vector_type(8))) short bf16x8;   // 8 bf16 (4 VGPRs)
typedef __attribute__((ext_vector_type(4))) float f32x4;

__device__ __forceinline__ unsigned short f2bf(float f) {
    union { float f; unsigned u; } v; v.f = f;
    unsigned r = (v.u + 0x7FFFu + ((v.u >> 16) & 1u)) >> 16;  // RNE
    return (unsigned short)r;
}
__device__ __forceinline__ float bf2f(unsigned short b) {
    union { unsigned u; float f; } v; v.u = ((unsigned)b) << 16;
    return v.f;
}

// ---------------------------------------------------------------------------
// CSR build (counting sort of edges by dst)
// ---------------------------------------------------------------------------
__global__ void hist_kernel(const int* __restrict__ dst, int* __restrict__ deg, int E) {
    int e = blockIdx.x * blockDim.x + threadIdx.x;
    if (e < E) atomicAdd(&deg[dst[e]], 1);
}

// 1024-thread wave-shuffle scan (16 waves), 3 barriers per chunk
__global__ void scan_kernel(const int* __restrict__ deg, int* __restrict__ row_ptr, int n) {
    __shared__ int wsum[16];
    __shared__ int carry_s, wtot_s;
    const int tid = threadIdx.x;
    const int lane = tid & 63;
    const int wid = tid >> 6;
    if (tid == 0) { carry_s = 0; row_ptr[0] = 0; }
    __syncthreads();
    for (int base = 0; base < n; base += 1024) {
        int i = base + tid;
        int x = (i < n) ? deg[i] : 0;
#pragma unroll
        for (int off = 1; off < 64; off <<= 1) {
            int t = __shfl_up(x, off, 64);
            if (lane >= off) x += t;
        }
        if (lane == 63) wsum[wid] = x;
        __syncthreads();
        if (tid == 0) {
            int s = 0;
#pragma unroll
            for (int j = 0; j < 16; ++j) { int t = wsum[j]; wsum[j] = s; s += t; }
            wtot_s = s;
        }
        __syncthreads();
        int incl = x + wsum[wid] + carry_s;
        if (i < n) row_ptr[i + 1] = incl;
        __syncthreads();
        if (tid == 0) carry_s += wtot_s;
        __syncthreads();
    }
}

__global__ void scatter_kernel(const int* __restrict__ src, const int* __restrict__ dst,
                               const int* __restrict__ row_ptr, int* __restrict__ cursor,
                               int* __restrict__ csr_src, int* __restrict__ csr_dst, int E) {
    int e = blockIdx.x * blockDim.x + threadIdx.x;
    if (e < E) {
        int d = dst[e];
        int pos = atomicAdd(&cursor[d], 1);
        int slot = row_ptr[d] + pos;
        csr_src[slot] = src[e];
        csr_dst[slot] = d;
    }
}

// ---------------------------------------------------------------------------
// fp32 -> bf16 convert (x -> h_bf at layer 0)
// ---------------------------------------------------------------------------
__global__ void convert_kernel(const float* __restrict__ in, unsigned short* __restrict__ out, int n4) {
    int i = blockIdx.x * blockDim.x + threadIdx.x;
    if (i < n4) {
        float4 v = *(const float4*)(in + (size_t)i * 4);
        ushort4 o;
        o.x = f2bf(v.x); o.y = f2bf(v.y); o.z = f2bf(v.z); o.w = f2bf(v.w);
        *(ushort4*)(out + (size_t)i * 4) = o;
    }
}

// ---------------------------------------------------------------------------
// Weight pack via LDS-tiled transpose: Wt[l][n][k] (bf16) from W*[l][k][n] (fp32)
// grid: (NC/32, 128/32, LAYERS), block 256 (32 cols x 8 rows)
// ---------------------------------------------------------------------------
__global__ __launch_bounds__(256) void pack_w_kernel(
    const float* __restrict__ Wq, const float* __restrict__ Wk,
    const float* __restrict__ Wv, const float* __restrict__ Ws,
    unsigned short* __restrict__ Wt)
{
    __shared__ unsigned short t[32][33];
    const int l  = blockIdx.z;
    const int k0 = blockIdx.y * 32;
    const int n0 = blockIdx.x * 32;
    const int cx = threadIdx.x & 31;
    const int ry = threadIdx.x >> 5;   // 0..7
#pragma unroll
    for (int rr = 0; rr < 32; rr += 8) {
        int k = k0 + ry + rr;
        int n = n0 + cx;
        float v;
        if (n < 512)       v = Wq[(size_t)l * 65536 + (size_t)k * 512 + n];
        else if (n < 1024) v = Wk[(size_t)l * 65536 + (size_t)k * 512 + (n - 512)];
        else if (n < 1536) v = Wv[(size_t)l * 65536 + (size_t)k * 512 + (n - 1024)];
        else               v = Ws[(size_t)l * 16384 + (size_t)k * 128 + (n - 1536)];
        t[ry + rr][cx] = f2bf(v);
    }
    __syncthreads();
#pragma unroll
    for (int rr = 0; rr < 32; rr += 8) {
        int n = n0 + ry + rr;
        int k = k0 + cx;
        Wt[(size_t)l * NC * 128 + (size_t)n * 128 + k] = t[cx][ry + rr];
    }
}

__global__ void pack_b_kernel(const float* __restrict__ bq, const float* __restrict__ bk,
                              const float* __restrict__ bv, const float* __restrict__ bs,
                              float* __restrict__ biasP) {
    int idx = blockIdx.x * blockDim.x + threadIdx.x;   // l*NC + n
    if (idx >= LAYERS * NC) return;
    int n = idx % NC;
    int l = idx / NC;
    float v;
    if (n < 512)       v = bq[(size_t)l * 512 + n];
    else if (n < 1024) v = bk[(size_t)l * 512 + (n - 512)];
    else if (n < 1536) v = bv[(size_t)l * 512 + (n - 1024)];
    else               v = bs[(size_t)l * 128 + (n - 1536)];
    biasP[idx] = v;
}

// ---------------------------------------------------------------------------
// Fused bf16 MFMA GEMM: C[M x 1664] = A[M x 128] @ Wt^T + bias
// 128x128 tile, 256 thr = 4 waves (2x2), each wave 64x64 via 4x4 of 16x16x32.
// ---------------------------------------------------------------------------
__global__ __launch_bounds__(256) void gemm_mfma(
    const unsigned short* __restrict__ Abf,   // [M][128] bf16
    const unsigned short* __restrict__ Wt,    // [NC][128] bf16 (layer base)
    const float* __restrict__ bias,           // [NC]
    unsigned short* __restrict__ Qb,          // [M][512] bf16
    unsigned short* __restrict__ Kb,
    unsigned short* __restrict__ Vb,
    float* __restrict__ Sb,                   // [M][128] fp32
    int M)
{
    __shared__ unsigned short As[128][72];    // 64+8 pad
    __shared__ unsigned short Bs[128][72];

    const int tid = threadIdx.x;
    const int wave = tid >> 6, lane = tid & 63;
    const int lane16 = lane & 15, quad = lane >> 4;
    const int wr = wave >> 1, wc = wave & 1;
    const int row0 = blockIdx.y * 128;
    const int col0 = blockIdx.x * 128;

    f32x4 acc[4][4] = {};

    for (int kk = 0; kk < 128; kk += 64) {
#pragma unroll
        for (int j = 0; j < 4; ++j) {
            int c = tid + j * 256;
            int r = c >> 3, c8 = (c & 7) * 8;
            bf16x8 v = {};
            if (row0 + r < M) v = *(const bf16x8*)(Abf + (size_t)(row0 + r) * 128 + kk + c8);
            *(bf16x8*)&As[r][c8] = v;
        }
#pragma unroll
        for (int j = 0; j < 4; ++j) {
            int c = tid + j * 256;
            int r = c >> 3, c8 = (c & 7) * 8;
            *(bf16x8*)&Bs[r][c8] = *(const bf16x8*)(Wt + (size_t)(col0 + r) * 128 + kk + c8);
        }
        __syncthreads();

#pragma unroll
        for (int ks = 0; ks < 2; ++ks) {
            bf16x8 a[4], b[4];
#pragma unroll
            for (int i = 0; i < 4; ++i)
                a[i] = *(const bf16x8*)&As[wr * 64 + i * 16 + lane16][ks * 32 + quad * 8];
#pragma unroll
            for (int i = 0; i < 4; ++i)
                b[i] = *(const bf16x8*)&Bs[wc * 64 + i * 16 + lane16][ks * 32 + quad * 8];
#pragma unroll
            for (int mi = 0; mi < 4; ++mi)
#pragma unroll
                for (int ni = 0; ni < 4; ++ni)
                    acc[mi][ni] = __builtin_amdgcn_mfma_f32_16x16x32_bf16(
                        a[mi], b[ni], acc[mi][ni], 0, 0, 0);
        }
        __syncthreads();
    }

    // Epilogue: C/D layout col = lane&15, row = quad*4 + reg
#pragma unroll
    for (int mi = 0; mi < 4; ++mi) {
        int rowb = row0 + wr * 64 + mi * 16 + quad * 4;
#pragma unroll
        for (int ni = 0; ni < 4; ++ni) {
            int col = col0 + wc * 64 + ni * 16 + lane16;
            float bv = bias[col];
#pragma unroll
            for (int r = 0; r < 4; ++r) {
                int gr = rowb + r;
                if (gr < M) {
                    float v = acc[mi][ni][r] + bv;
                    if (col0 < 512)       Qb[(size_t)gr * 512 + col] = f2bf(v);
                    else if (col0 < 1024) Kb[(size_t)gr * 512 + (col - 512)] = f2bf(v);
                    else if (col0 < 1536) Vb[(size_t)gr * 512 + (col - 1024)] = f2bf(v);
                    else                  Sb[(size_t)gr * 128 + (col - 1536)] = v;
                }
            }
        }
    }
}

// ---------------------------------------------------------------------------
// Attention phase A: edge-parallel alpha. One wave per 4 edges; per edge each
// lane loads 16B (8ch) of K[src] and Q[dst] full rows; reduce within 16-lane
// head groups (4 shuffles). alpha stored planar [h][E].
// ---------------------------------------------------------------------------
__global__ __launch_bounds__(256) void alpha_kernel(
    const unsigned short* __restrict__ Q,    // [N][512] bf16
    const unsigned short* __restrict__ K,
    const int* __restrict__ csr_src,
    const int* __restrict__ csr_dst,
    float* __restrict__ alpha,               // [H][E]
    int E)
{
    const int lane = threadIdx.x & 63;
    const int wid = (blockIdx.x * blockDim.x + threadIdx.x) >> 6;
    const int e0 = wid * 4;
    if (e0 >= E) return;
    const int cnt = (e0 + 4 <= E) ? 4 : (E - e0);
    const int c0 = lane * 8;
    const float scale = 0.08838834764831845f;   // 1/sqrt(128)

    bf16x8 kv[4], qv[4];
    for (int j = 0; j < cnt; ++j) {
        int s = csr_src[e0 + j];
        int d = csr_dst[e0 + j];
        kv[j] = *(const bf16x8*)(K + (size_t)s * HF + c0);
        qv[j] = *(const bf16x8*)(Q + (size_t)d * HF + c0);
    }
    float p[4];
    for (int j = 0; j < cnt; ++j) {
        float t = 0.f;
#pragma unroll
        for (int i = 0; i < 8; ++i)
            t += bf2f((unsigned short)kv[j][i]) * bf2f((unsigned short)qv[j][i]);
        p[j] = t;
    }
    for (int j = 0; j < cnt; ++j) {
#pragma unroll
        for (int off = 1; off < 16; off <<= 1)
            p[j] += __shfl_xor(p[j], off, 64);
        p[j] *= scale;
    }
    if ((lane & 15) == 0) {
        int h = lane >> 4;
        float* ap = alpha + (size_t)h * E + e0;
        if (cnt == 4) {
            float4 o = make_float4(p[0], p[1], p[2], p[3]);
            *(float4*)ap = o;
        } else {
            for (int j = 0; j < cnt; ++j) ap[j] = p[j];
        }
    }
}

// ---------------------------------------------------------------------------
// Attention phase B: per-node softmax + V aggregation + head-mean + skip.
// Block per node, wave h = head h. True max/sum via one butterfly per node;
// aggregation loop has no serial dependence.
// ---------------------------------------------------------------------------
__global__ __launch_bounds__(256) void aggregate_kernel(
    const unsigned short* __restrict__ V,    // [N][512] bf16
    const float* __restrict__ S,             // [N][128]
    const float* __restrict__ alpha,         // [H][E]
    const int* __restrict__ row_ptr,
    const int* __restrict__ csr_src,
    float* __restrict__ out_f,
    unsigned short* __restrict__ out_bf,
    int relu, int N, int E)
{
    const int node = blockIdx.x;
    if (node >= N) return;
    const int h = threadIdx.x >> 6;
    const int lane = threadIdx.x & 63;
    const float* al = alpha + (size_t)h * E;

    const int beg = row_ptr[node];
    const int end = row_ptr[node + 1];

    // max over this node's alphas (head h)
    float m = -INFINITY;
    for (int i = beg + lane; i < end; i += 64) m = fmaxf(m, al[i]);
#pragma unroll
    for (int off = 32; off > 0; off >>= 1) m = fmaxf(m, __shfl_xor(m, off, 64));

    // denom
    float z = 0.f;
    for (int i = beg + lane; i < end; i += 64) z += __expf(al[i] - m);
#pragma unroll
    for (int off = 32; off > 0; off >>= 1) z += __shfl_xor(z, off, 64);

    // aggregate: lane covers 2 channels of head h
    const unsigned short* Vh = V + (size_t)h * F + lane * 2;
    float acc0 = 0.f, acc1 = 0.f;
    int i = beg;
    for (; i + 2 <= end; i += 2) {
        int s0 = csr_src[i], s1 = csr_src[i + 1];
        float w0 = __expf(al[i] - m);
        float w1 = __expf(al[i + 1] - m);
        unsigned vu0 = *(const unsigned*)(Vh + (size_t)s0 * HF);
        unsigned vu1 = *(const unsigned*)(Vh + (size_t)s1 * HF);
        acc0 += w0 * bf2f((unsigned short)(vu0 & 0xffff)) + w1 * bf2f((unsigned short)(vu1 & 0xffff));
        acc1 += w0 * bf2f((unsigned short)(vu0 >> 16)) + w1 * bf2f((unsigned short)(vu1 >> 16));
    }
    if (i < end) {
        int s0 = csr_src[i];
        float w0 = __expf(al[i] - m);
        unsigned vu0 = *(const unsigned*)(Vh + (size_t)s0 * HF);
        acc0 += w0 * bf2f((unsigned short)(vu0 & 0xffff));
        acc1 += w0 * bf2f((unsigned short)(vu0 >> 16));
    }

    float inv = (z > 0.f) ? 1.f / z : 0.f;

    __shared__ float sm[H][F];
    sm[h][lane * 2 + 0] = acc0 * inv;
    sm[h][lane * 2 + 1] = acc1 * inv;
    __syncthreads();

    if (threadIdx.x < F) {
        int c = threadIdx.x;
        float o = 0.25f * (sm[0][c] + sm[1][c] + sm[2][c] + sm[3][c])
                + S[(size_t)node * F + c];
        if (relu) o = fmaxf(o, 0.f);
        if (out_f)  out_f[(size_t)node * F + c] = o;
        if (out_bf) out_bf[(size_t)node * F + c] = f2bf(o);
    }
}

// ---------------------------------------------------------------------------
// Launch
// ---------------------------------------------------------------------------
extern "C" void kernel_launch(void* const* d_in, const int* in_sizes, int n_in,
                              void* d_out, int out_size, void* d_ws, size_t ws_size,
                              hipStream_t stream) {
    const float* x     = (const float*)d_in[0];
    const int*   ei    = (const int*)d_in[1];
    const float* Wq    = (const float*)d_in[2];
    const float* bq    = (const float*)d_in[3];
    const float* Wk    = (const float*)d_in[4];
    const float* bk    = (const float*)d_in[5];
    const float* Wv    = (const float*)d_in[6];
    const float* bv    = (const float*)d_in[7];
    const float* Wskip = (const float*)d_in[8];
    const float* bskip = (const float*)d_in[9];
    float* out = (float*)d_out;

    const int N = in_sizes[0] / F;       // 10000
    const int E = in_sizes[1] / 2;       // 160000

    const int* src = ei;
    const int* dst = ei + E;

    // Workspace layout
    char* p = (char*)d_ws;
    float* Sb    = (float*)p;                 p += (size_t)N * F * sizeof(float);
    float* biasP = (float*)p;                 p += (size_t)LAYERS * NC * sizeof(float);
    float* alphaB = (float*)p;                p += (size_t)H * E * sizeof(float);
    unsigned short* h_bf = (unsigned short*)p; p += (size_t)N * F * sizeof(unsigned short);
    unsigned short* Qb   = (unsigned short*)p; p += (size_t)N * HF * sizeof(unsigned short);
    unsigned short* Kb   = (unsigned short*)p; p += (size_t)N * HF * sizeof(unsigned short);
    unsigned short* Vb   = (unsigned short*)p; p += (size_t)N * HF * sizeof(unsigned short);
    unsigned short* WtP  = (unsigned short*)p; p += (size_t)LAYERS * NC * 128 * sizeof(unsigned short);
    int* deg     = (int*)p;                   p += (size_t)N * sizeof(int);
    int* cursor  = (int*)p;                   p += (size_t)N * sizeof(int);
    int* row_ptr = (int*)p;                   p += (size_t)(N + 1) * sizeof(int);
    int* csr_src = (int*)p;                   p += (size_t)E * sizeof(int);
    int* csr_dst = (int*)p;

    // --- CSR build
    hipMemsetAsync(deg, 0, 2 * (size_t)N * sizeof(int), stream);  // deg + cursor
    {
        int blocks = (E + 255) / 256;
        hist_kernel<<<blocks, 256, 0, stream>>>(dst, deg, E);
        scan_kernel<<<1, 1024, 0, stream>>>(deg, row_ptr, N);
        scatter_kernel<<<blocks, 256, 0, stream>>>(src, dst, row_ptr, cursor, csr_src, csr_dst, E);
    }

    // --- One-time packs/converts
    convert_kernel<<<(N * F / 4 + 255) / 256, 256, 0, stream>>>(x, h_bf, N * F / 4);
    {
        dim3 g(NC / 32, 128 / 32, LAYERS);
        pack_w_kernel<<<g, 256, 0, stream>>>(Wq, Wk, Wv, Wskip, WtP);
    }
    pack_b_kernel<<<(LAYERS * NC + 255) / 256, 256, 0, stream>>>(bq, bk, bv, bskip, biasP);

    const int rowBlocks = (N + 127) / 128;
    const int alphaBlocks = (E + 15) / 16;   // 4 waves x 4 edges per block

    for (int l = 0; l < LAYERS; ++l) {
        dim3 grid(NC / 128, rowBlocks);
        gemm_mfma<<<grid, 256, 0, stream>>>(h_bf,
                                            WtP + (size_t)l * NC * 128,
                                            biasP + (size_t)l * NC,
                                            Qb, Kb, Vb, Sb, N);

        alpha_kernel<<<alphaBlocks, 256, 0, stream>>>(Qb, Kb, csr_src, csr_dst,
                                                      alphaB, E);

        float* out_f = nullptr;
        unsigned short* out_bf = nullptr;
        int relu;
        if (l == LAYERS - 1) { out_f = out; relu = 0; }
        else { out_bf = h_bf; relu = 1; }

        aggregate_kernel<<<N, 256, 0, stream>>>(Vb, Sb, alphaB, row_ptr, csr_src,
                                                out_f, out_bf, relu, N, E);
    }
}

// Round 4
// 468.978 us; speedup vs baseline: 4.1406x; 4.1406x over previous
//
#include <hip/hip_runtime.h>
#include <math.h>

static constexpr int F  = 128;    // channels per head
static constexpr int H  = 4;      // heads
static constexpr int HF = 512;    // H*F
static constexpr int NC = 1664;   // packed GEMM cols: Q(512)|K(512)|V(512)|S(128)
static constexpr int LAYERS = 4;

typedef __attribute__((ext_vector_type(8))) short bf16x8;   // 8 bf16 (4 VGPRs)
typedef __attribute__((ext_vector_type(4))) float f32x4;

__device__ __forceinline__ unsigned short f2bf(float f) {
    union { float f; unsigned u; } v; v.f = f;
    unsigned r = (v.u + 0x7FFFu + ((v.u >> 16) & 1u)) >> 16;  // RNE
    return (unsigned short)r;
}
__device__ __forceinline__ float bf2f(unsigned short b) {
    union { unsigned u; float f; } v; v.u = ((unsigned)b) << 16;
    return v.f;
}

// ---------------------------------------------------------------------------
// CSR build (counting sort of edges by dst)
// ---------------------------------------------------------------------------
__global__ void hist_kernel(const int* __restrict__ dst, int* __restrict__ deg, int E) {
    int e = blockIdx.x * blockDim.x + threadIdx.x;
    if (e < E) atomicAdd(&deg[dst[e]], 1);
}

// 1024-thread wave-shuffle scan (16 waves), 3 barriers per chunk
__global__ void scan_kernel(const int* __restrict__ deg, int* __restrict__ row_ptr, int n) {
    __shared__ int wsum[16];
    __shared__ int carry_s, wtot_s;
    const int tid = threadIdx.x;
    const int lane = tid & 63;
    const int wid = tid >> 6;
    if (tid == 0) { carry_s = 0; row_ptr[0] = 0; }
    __syncthreads();
    for (int base = 0; base < n; base += 1024) {
        int i = base + tid;
        int x = (i < n) ? deg[i] : 0;
#pragma unroll
        for (int off = 1; off < 64; off <<= 1) {
            int t = __shfl_up(x, off, 64);
            if (lane >= off) x += t;
        }
        if (lane == 63) wsum[wid] = x;
        __syncthreads();
        if (tid == 0) {
            int s = 0;
#pragma unroll
            for (int j = 0; j < 16; ++j) { int t = wsum[j]; wsum[j] = s; s += t; }
            wtot_s = s;
        }
        __syncthreads();
        int incl = x + wsum[wid] + carry_s;
        if (i < n) row_ptr[i + 1] = incl;
        __syncthreads();
        if (tid == 0) carry_s += wtot_s;
        __syncthreads();
    }
}

__global__ void scatter_kernel(const int* __restrict__ src, const int* __restrict__ dst,
                               const int* __restrict__ row_ptr, int* __restrict__ cursor,
                               int* __restrict__ csr_src, int* __restrict__ csr_dst, int E) {
    int e = blockIdx.x * blockDim.x + threadIdx.x;
    if (e < E) {
        int d = dst[e];
        int pos = atomicAdd(&cursor[d], 1);
        int slot = row_ptr[d] + pos;
        csr_src[slot] = src[e];
        csr_dst[slot] = d;
    }
}

// ---------------------------------------------------------------------------
// fp32 -> bf16 convert (x -> h_bf at layer 0)
// ---------------------------------------------------------------------------
__global__ void convert_kernel(const float* __restrict__ in, unsigned short* __restrict__ out, int n4) {
    int i = blockIdx.x * blockDim.x + threadIdx.x;
    if (i < n4) {
        float4 v = *(const float4*)(in + (size_t)i * 4);
        ushort4 o;
        o.x = f2bf(v.x); o.y = f2bf(v.y); o.z = f2bf(v.z); o.w = f2bf(v.w);
        *(ushort4*)(out + (size_t)i * 4) = o;
    }
}

// ---------------------------------------------------------------------------
// Weight pack via LDS-tiled transpose: Wt[l][n][k] (bf16) from W*[l][k][n] (fp32)
// ---------------------------------------------------------------------------
__global__ __launch_bounds__(256) void pack_w_kernel(
    const float* __restrict__ Wq, const float* __restrict__ Wk,
    const float* __restrict__ Wv, const float* __restrict__ Ws,
    unsigned short* __restrict__ Wt)
{
    __shared__ unsigned short t[32][33];
    const int l  = blockIdx.z;
    const int k0 = blockIdx.y * 32;
    const int n0 = blockIdx.x * 32;
    const int cx = threadIdx.x & 31;
    const int ry = threadIdx.x >> 5;   // 0..7
#pragma unroll
    for (int rr = 0; rr < 32; rr += 8) {
        int k = k0 + ry + rr;
        int n = n0 + cx;
        float v;
        if (n < 512)       v = Wq[(size_t)l * 65536 + (size_t)k * 512 + n];
        else if (n < 1024) v = Wk[(size_t)l * 65536 + (size_t)k * 512 + (n - 512)];
        else if (n < 1536) v = Wv[(size_t)l * 65536 + (size_t)k * 512 + (n - 1024)];
        else               v = Ws[(size_t)l * 16384 + (size_t)k * 128 + (n - 1536)];
        t[ry + rr][cx] = f2bf(v);
    }
    __syncthreads();
#pragma unroll
    for (int rr = 0; rr < 32; rr += 8) {
        int n = n0 + ry + rr;
        int k = k0 + cx;
        Wt[(size_t)l * NC * 128 + (size_t)n * 128 + k] = t[cx][ry + rr];
    }
}

__global__ void pack_b_kernel(const float* __restrict__ bq, const float* __restrict__ bk,
                              const float* __restrict__ bv, const float* __restrict__ bs,
                              float* __restrict__ biasP) {
    int idx = blockIdx.x * blockDim.x + threadIdx.x;   // l*NC + n
    if (idx >= LAYERS * NC) return;
    int n = idx % NC;
    int l = idx / NC;
    float v;
    if (n < 512)       v = bq[(size_t)l * 512 + n];
    else if (n < 1024) v = bk[(size_t)l * 512 + (n - 512)];
    else if (n < 1536) v = bv[(size_t)l * 512 + (n - 1024)];
    else               v = bs[(size_t)l * 128 + (n - 1536)];
    biasP[idx] = v;
}

// ---------------------------------------------------------------------------
// Fused bf16 MFMA GEMM: C[M x 1664] = A[M x 128] @ Wt^T + bias
// ---------------------------------------------------------------------------
__global__ __launch_bounds__(256) void gemm_mfma(
    const unsigned short* __restrict__ Abf,   // [M][128] bf16
    const unsigned short* __restrict__ Wt,    // [NC][128] bf16 (layer base)
    const float* __restrict__ bias,           // [NC]
    unsigned short* __restrict__ Qb,          // [M][512] bf16
    unsigned short* __restrict__ Kb,
    unsigned short* __restrict__ Vb,
    float* __restrict__ Sb,                   // [M][128] fp32
    int M)
{
    __shared__ unsigned short As[128][72];    // 64+8 pad
    __shared__ unsigned short Bs[128][72];

    const int tid = threadIdx.x;
    const int wave = tid >> 6, lane = tid & 63;
    const int lane16 = lane & 15, quad = lane >> 4;
    const int wr = wave >> 1, wc = wave & 1;
    const int row0 = blockIdx.y * 128;
    const int col0 = blockIdx.x * 128;

    f32x4 acc[4][4] = {};

    for (int kk = 0; kk < 128; kk += 64) {
#pragma unroll
        for (int j = 0; j < 4; ++j) {
            int c = tid + j * 256;
            int r = c >> 3, c8 = (c & 7) * 8;
            bf16x8 v = {};
            if (row0 + r < M) v = *(const bf16x8*)(Abf + (size_t)(row0 + r) * 128 + kk + c8);
            *(bf16x8*)&As[r][c8] = v;
        }
#pragma unroll
        for (int j = 0; j < 4; ++j) {
            int c = tid + j * 256;
            int r = c >> 3, c8 = (c & 7) * 8;
            *(bf16x8*)&Bs[r][c8] = *(const bf16x8*)(Wt + (size_t)(col0 + r) * 128 + kk + c8);
        }
        __syncthreads();

#pragma unroll
        for (int ks = 0; ks < 2; ++ks) {
            bf16x8 a[4], b[4];
#pragma unroll
            for (int i = 0; i < 4; ++i)
                a[i] = *(const bf16x8*)&As[wr * 64 + i * 16 + lane16][ks * 32 + quad * 8];
#pragma unroll
            for (int i = 0; i < 4; ++i)
                b[i] = *(const bf16x8*)&Bs[wc * 64 + i * 16 + lane16][ks * 32 + quad * 8];
#pragma unroll
            for (int mi = 0; mi < 4; ++mi)
#pragma unroll
                for (int ni = 0; ni < 4; ++ni)
                    acc[mi][ni] = __builtin_amdgcn_mfma_f32_16x16x32_bf16(
                        a[mi], b[ni], acc[mi][ni], 0, 0, 0);
        }
        __syncthreads();
    }

    // Epilogue: C/D layout col = lane&15, row = quad*4 + reg
#pragma unroll
    for (int mi = 0; mi < 4; ++mi) {
        int rowb = row0 + wr * 64 + mi * 16 + quad * 4;
#pragma unroll
        for (int ni = 0; ni < 4; ++ni) {
            int col = col0 + wc * 64 + ni * 16 + lane16;
            float bv = bias[col];
#pragma unroll
            for (int r = 0; r < 4; ++r) {
                int gr = rowb + r;
                if (gr < M) {
                    float v = acc[mi][ni][r] + bv;
                    if (col0 < 512)       Qb[(size_t)gr * 512 + col] = f2bf(v);
                    else if (col0 < 1024) Kb[(size_t)gr * 512 + (col - 512)] = f2bf(v);
                    else if (col0 < 1536) Vb[(size_t)gr * 512 + (col - 1024)] = f2bf(v);
                    else                  Sb[(size_t)gr * 128 + (col - 1536)] = v;
                }
            }
        }
    }
}

// ---------------------------------------------------------------------------
// Attention phase A: edge-parallel alpha. One wave per 4 edges (FULLY
// UNROLLED — no dynamic array indexing, everything stays in VGPRs).
// Per edge each lane loads 16B (8ch) of K[src] and Q[dst]; reduce within
// 16-lane head groups (4 shuffles). alpha stored planar [h][E].
// ---------------------------------------------------------------------------
__global__ __launch_bounds__(256) void alpha_kernel(
    const unsigned short* __restrict__ Q,    // [N][512] bf16
    const unsigned short* __restrict__ K,
    const int* __restrict__ csr_src,
    const int* __restrict__ csr_dst,
    float* __restrict__ alpha,               // [H][E]
    int E)
{
    const int lane = threadIdx.x & 63;
    const int wid = (blockIdx.x * blockDim.x + threadIdx.x) >> 6;
    const int e0 = wid * 4;
    if (e0 >= E) return;
    const int c0 = lane * 8;
    const float scale = 0.08838834764831845f;   // 1/sqrt(128)

    bf16x8 kv[4], qv[4];
#pragma unroll
    for (int j = 0; j < 4; ++j) {
        int e = e0 + j; if (e > E - 1) e = E - 1;    // clamp tail (stores guarded)
        int s = csr_src[e];
        int d = csr_dst[e];
        kv[j] = *(const bf16x8*)(K + (size_t)s * HF + c0);
        qv[j] = *(const bf16x8*)(Q + (size_t)d * HF + c0);
    }
    float p[4];
#pragma unroll
    for (int j = 0; j < 4; ++j) {
        float t = 0.f;
#pragma unroll
        for (int i = 0; i < 8; ++i)
            t += bf2f((unsigned short)kv[j][i]) * bf2f((unsigned short)qv[j][i]);
        p[j] = t;
    }
#pragma unroll
    for (int j = 0; j < 4; ++j) {
#pragma unroll
        for (int off = 1; off < 16; off <<= 1)
            p[j] += __shfl_xor(p[j], off, 64);
        p[j] *= scale;
    }
    if ((lane & 15) == 0) {
        int h = lane >> 4;
        float* ap = alpha + (size_t)h * E + e0;
        if (e0 + 4 <= E) {
            *(float4*)ap = make_float4(p[0], p[1], p[2], p[3]);
        } else {
#pragma unroll
            for (int j = 0; j < 4; ++j)
                if (e0 + j < E) ap[j] = p[j];
        }
    }
}

// ---------------------------------------------------------------------------
// Attention phase B: per-node softmax + V aggregation + head-mean + skip.
// ---------------------------------------------------------------------------
__global__ __launch_bounds__(256) void aggregate_kernel(
    const unsigned short* __restrict__ V,    // [N][512] bf16
    const float* __restrict__ S,             // [N][128]
    const float* __restrict__ alpha,         // [H][E]
    const int* __restrict__ row_ptr,
    const int* __restrict__ csr_src,
    float* __restrict__ out_f,
    unsigned short* __restrict__ out_bf,
    int relu, int N, int E)
{
    const int node = blockIdx.x;
    if (node >= N) return;
    const int h = threadIdx.x >> 6;
    const int lane = threadIdx.x & 63;
    const float* al = alpha + (size_t)h * E;

    const int beg = row_ptr[node];
    const int end = row_ptr[node + 1];

    // max over this node's alphas (head h)
    float m = -INFINITY;
    for (int i = beg + lane; i < end; i += 64) m = fmaxf(m, al[i]);
#pragma unroll
    for (int off = 32; off > 0; off >>= 1) m = fmaxf(m, __shfl_xor(m, off, 64));

    // denom
    float z = 0.f;
    for (int i = beg + lane; i < end; i += 64) z += __expf(al[i] - m);
#pragma unroll
    for (int off = 32; off > 0; off >>= 1) z += __shfl_xor(z, off, 64);

    // aggregate: lane covers 2 channels of head h
    const unsigned short* Vh = V + (size_t)h * F + lane * 2;
    float acc0 = 0.f, acc1 = 0.f;
    int i = beg;
    for (; i + 2 <= end; i += 2) {
        int s0 = csr_src[i], s1 = csr_src[i + 1];
        float w0 = __expf(al[i] - m);
        float w1 = __expf(al[i + 1] - m);
        unsigned vu0 = *(const unsigned*)(Vh + (size_t)s0 * HF);
        unsigned vu1 = *(const unsigned*)(Vh + (size_t)s1 * HF);
        acc0 += w0 * bf2f((unsigned short)(vu0 & 0xffff)) + w1 * bf2f((unsigned short)(vu1 & 0xffff));
        acc1 += w0 * bf2f((unsigned short)(vu0 >> 16)) + w1 * bf2f((unsigned short)(vu1 >> 16));
    }
    if (i < end) {
        int s0 = csr_src[i];
        float w0 = __expf(al[i] - m);
        unsigned vu0 = *(const unsigned*)(Vh + (size_t)s0 * HF);
        acc0 += w0 * bf2f((unsigned short)(vu0 & 0xffff));
        acc1 += w0 * bf2f((unsigned short)(vu0 >> 16));
    }

    float inv = (z > 0.f) ? 1.f / z : 0.f;

    __shared__ float sm[H][F];
    sm[h][lane * 2 + 0] = acc0 * inv;
    sm[h][lane * 2 + 1] = acc1 * inv;
    __syncthreads();

    if (threadIdx.x < F) {
        int c = threadIdx.x;
        float o = 0.25f * (sm[0][c] + sm[1][c] + sm[2][c] + sm[3][c])
                + S[(size_t)node * F + c];
        if (relu) o = fmaxf(o, 0.f);
        if (out_f)  out_f[(size_t)node * F + c] = o;
        if (out_bf) out_bf[(size_t)node * F + c] = f2bf(o);
    }
}

// ---------------------------------------------------------------------------
// Launch
// ---------------------------------------------------------------------------
extern "C" void kernel_launch(void* const* d_in, const int* in_sizes, int n_in,
                              void* d_out, int out_size, void* d_ws, size_t ws_size,
                              hipStream_t stream) {
    const float* x     = (const float*)d_in[0];
    const int*   ei    = (const int*)d_in[1];
    const float* Wq    = (const float*)d_in[2];
    const float* bq    = (const float*)d_in[3];
    const float* Wk    = (const float*)d_in[4];
    const float* bk    = (const float*)d_in[5];
    const float* Wv    = (const float*)d_in[6];
    const float* bv    = (const float*)d_in[7];
    const float* Wskip = (const float*)d_in[8];
    const float* bskip = (const float*)d_in[9];
    float* out = (float*)d_out;

    const int N = in_sizes[0] / F;       // 10000
    const int E = in_sizes[1] / 2;       // 160000

    const int* src = ei;
    const int* dst = ei + E;

    // Workspace layout
    char* p = (char*)d_ws;
    float* Sb    = (float*)p;                 p += (size_t)N * F * sizeof(float);
    float* biasP = (float*)p;                 p += (size_t)LAYERS * NC * sizeof(float);
    float* alphaB = (float*)p;                p += (size_t)H * E * sizeof(float);
    unsigned short* h_bf = (unsigned short*)p; p += (size_t)N * F * sizeof(unsigned short);
    unsigned short* Qb   = (unsigned short*)p; p += (size_t)N * HF * sizeof(unsigned short);
    unsigned short* Kb   = (unsigned short*)p; p += (size_t)N * HF * sizeof(unsigned short);
    unsigned short* Vb   = (unsigned short*)p; p += (size_t)N * HF * sizeof(unsigned short);
    unsigned short* WtP  = (unsigned short*)p; p += (size_t)LAYERS * NC * 128 * sizeof(unsigned short);
    int* deg     = (int*)p;                   p += (size_t)N * sizeof(int);
    int* cursor  = (int*)p;                   p += (size_t)N * sizeof(int);
    int* row_ptr = (int*)p;                   p += (size_t)(N + 1) * sizeof(int);
    int* csr_src = (int*)p;                   p += (size_t)E * sizeof(int);
    int* csr_dst = (int*)p;

    // --- CSR build
    hipMemsetAsync(deg, 0, 2 * (size_t)N * sizeof(int), stream);  // deg + cursor
    {
        int blocks = (E + 255) / 256;
        hist_kernel<<<blocks, 256, 0, stream>>>(dst, deg, E);
        scan_kernel<<<1, 1024, 0, stream>>>(deg, row_ptr, N);
        scatter_kernel<<<blocks, 256, 0, stream>>>(src, dst, row_ptr, cursor, csr_src, csr_dst, E);
    }

    // --- One-time packs/converts
    convert_kernel<<<(N * F / 4 + 255) / 256, 256, 0, stream>>>(x, h_bf, N * F / 4);
    {
        dim3 g(NC / 32, 128 / 32, LAYERS);
        pack_w_kernel<<<g, 256, 0, stream>>>(Wq, Wk, Wv, Wskip, WtP);
    }
    pack_b_kernel<<<(LAYERS * NC + 255) / 256, 256, 0, stream>>>(bq, bk, bv, bskip, biasP);

    const int rowBlocks = (N + 127) / 128;
    const int alphaBlocks = (E + 15) / 16;   // 4 waves x 4 edges per block

    for (int l = 0; l < LAYERS; ++l) {
        dim3 grid(NC / 128, rowBlocks);
        gemm_mfma<<<grid, 256, 0, stream>>>(h_bf,
                                            WtP + (size_t)l * NC * 128,
                                            biasP + (size_t)l * NC,
                                            Qb, Kb, Vb, Sb, N);

        alpha_kernel<<<alphaBlocks, 256, 0, stream>>>(Qb, Kb, csr_src, csr_dst,
                                                      alphaB, E);

        float* out_f = nullptr;
        unsigned short* out_bf = nullptr;
        int relu;
        if (l == LAYERS - 1) { out_f = out; relu = 0; }
        else { out_bf = h_bf; relu = 1; }

        aggregate_kernel<<<N, 256, 0, stream>>>(Vb, Sb, alphaB, row_ptr, csr_src,
                                                out_f, out_bf, relu, N, E);
    }
}

// Round 5
// 442.677 us; speedup vs baseline: 4.3866x; 1.0594x over previous
//
#include <hip/hip_runtime.h>
#include <math.h>

static constexpr int F  = 128;    // channels per head
static constexpr int H  = 4;      // heads
static constexpr int HF = 512;    // H*F
static constexpr int NC = 1664;   // packed GEMM cols: Q(512)|K(512)|V(512)|S(128)
static constexpr int LAYERS = 4;

typedef __attribute__((ext_vector_type(8))) short bf16x8;   // 8 bf16 (4 VGPRs)
typedef __attribute__((ext_vector_type(4))) float f32x4;

__device__ __forceinline__ unsigned short f2bf(float f) {
    union { float f; unsigned u; } v; v.f = f;
    unsigned r = (v.u + 0x7FFFu + ((v.u >> 16) & 1u)) >> 16;  // RNE
    return (unsigned short)r;
}
__device__ __forceinline__ float bf2f(unsigned short b) {
    union { unsigned u; float f; } v; v.u = ((unsigned)b) << 16;
    return v.f;
}

// ---------------------------------------------------------------------------
// CSR build (counting sort of edges by dst)
// ---------------------------------------------------------------------------
__global__ void hist_kernel(const int* __restrict__ dst, int* __restrict__ deg, int E) {
    int e = blockIdx.x * blockDim.x + threadIdx.x;
    if (e < E) atomicAdd(&deg[dst[e]], 1);
}

// 1024-thread wave-shuffle scan (16 waves), 3 barriers per chunk
__global__ void scan_kernel(const int* __restrict__ deg, int* __restrict__ row_ptr, int n) {
    __shared__ int wsum[16];
    __shared__ int carry_s, wtot_s;
    const int tid = threadIdx.x;
    const int lane = tid & 63;
    const int wid = tid >> 6;
    if (tid == 0) { carry_s = 0; row_ptr[0] = 0; }
    __syncthreads();
    for (int base = 0; base < n; base += 1024) {
        int i = base + tid;
        int x = (i < n) ? deg[i] : 0;
#pragma unroll
        for (int off = 1; off < 64; off <<= 1) {
            int t = __shfl_up(x, off, 64);
            if (lane >= off) x += t;
        }
        if (lane == 63) wsum[wid] = x;
        __syncthreads();
        if (tid == 0) {
            int s = 0;
#pragma unroll
            for (int j = 0; j < 16; ++j) { int t = wsum[j]; wsum[j] = s; s += t; }
            wtot_s = s;
        }
        __syncthreads();
        int incl = x + wsum[wid] + carry_s;
        if (i < n) row_ptr[i + 1] = incl;
        __syncthreads();
        if (tid == 0) carry_s += wtot_s;
        __syncthreads();
    }
}

__global__ void scatter_kernel(const int* __restrict__ src, const int* __restrict__ dst,
                               const int* __restrict__ row_ptr, int* __restrict__ cursor,
                               int* __restrict__ csr_src, int* __restrict__ csr_dst, int E) {
    int e = blockIdx.x * blockDim.x + threadIdx.x;
    if (e < E) {
        int d = dst[e];
        int pos = atomicAdd(&cursor[d], 1);
        int slot = row_ptr[d] + pos;
        csr_src[slot] = src[e];
        csr_dst[slot] = d;
    }
}

// ---------------------------------------------------------------------------
// fp32 -> bf16 convert (x -> h_bf at layer 0)
// ---------------------------------------------------------------------------
__global__ void convert_kernel(const float* __restrict__ in, unsigned short* __restrict__ out, int n4) {
    int i = blockIdx.x * blockDim.x + threadIdx.x;
    if (i < n4) {
        float4 v = *(const float4*)(in + (size_t)i * 4);
        ushort4 o;
        o.x = f2bf(v.x); o.y = f2bf(v.y); o.z = f2bf(v.z); o.w = f2bf(v.w);
        *(ushort4*)(out + (size_t)i * 4) = o;
    }
}

// ---------------------------------------------------------------------------
// Weight pack via LDS-tiled transpose: Wt[l][n][k] (bf16) from W*[l][k][n] (fp32)
// ---------------------------------------------------------------------------
__global__ __launch_bounds__(256) void pack_w_kernel(
    const float* __restrict__ Wq, const float* __restrict__ Wk,
    const float* __restrict__ Wv, const float* __restrict__ Ws,
    unsigned short* __restrict__ Wt)
{
    __shared__ unsigned short t[32][33];
    const int l  = blockIdx.z;
    const int k0 = blockIdx.y * 32;
    const int n0 = blockIdx.x * 32;
    const int cx = threadIdx.x & 31;
    const int ry = threadIdx.x >> 5;   // 0..7
#pragma unroll
    for (int rr = 0; rr < 32; rr += 8) {
        int k = k0 + ry + rr;
        int n = n0 + cx;
        float v;
        if (n < 512)       v = Wq[(size_t)l * 65536 + (size_t)k * 512 + n];
        else if (n < 1024) v = Wk[(size_t)l * 65536 + (size_t)k * 512 + (n - 512)];
        else if (n < 1536) v = Wv[(size_t)l * 65536 + (size_t)k * 512 + (n - 1024)];
        else               v = Ws[(size_t)l * 16384 + (size_t)k * 128 + (n - 1536)];
        t[ry + rr][cx] = f2bf(v);
    }
    __syncthreads();
#pragma unroll
    for (int rr = 0; rr < 32; rr += 8) {
        int n = n0 + ry + rr;
        int k = k0 + cx;
        Wt[(size_t)l * NC * 128 + (size_t)n * 128 + k] = t[cx][ry + rr];
    }
}

__global__ void pack_b_kernel(const float* __restrict__ bq, const float* __restrict__ bk,
                              const float* __restrict__ bv, const float* __restrict__ bs,
                              float* __restrict__ biasP) {
    int idx = blockIdx.x * blockDim.x + threadIdx.x;   // l*NC + n
    if (idx >= LAYERS * NC) return;
    int n = idx % NC;
    int l = idx / NC;
    float v;
    if (n < 512)       v = bq[(size_t)l * 512 + n];
    else if (n < 1024) v = bk[(size_t)l * 512 + (n - 512)];
    else if (n < 1536) v = bv[(size_t)l * 512 + (n - 1024)];
    else               v = bs[(size_t)l * 128 + (n - 1536)];
    biasP[idx] = v;
}

// ---------------------------------------------------------------------------
// Fused bf16 MFMA GEMM: C[M x 1664] = A[M x 128] @ Wt^T + bias
// ---------------------------------------------------------------------------
__global__ __launch_bounds__(256) void gemm_mfma(
    const unsigned short* __restrict__ Abf,   // [M][128] bf16
    const unsigned short* __restrict__ Wt,    // [NC][128] bf16 (layer base)
    const float* __restrict__ bias,           // [NC]
    unsigned short* __restrict__ Qb,          // [M][512] bf16
    unsigned short* __restrict__ Kb,
    unsigned short* __restrict__ Vb,
    float* __restrict__ Sb,                   // [M][128] fp32
    int M)
{
    __shared__ unsigned short As[128][72];    // 64+8 pad
    __shared__ unsigned short Bs[128][72];

    const int tid = threadIdx.x;
    const int wave = tid >> 6, lane = tid & 63;
    const int lane16 = lane & 15, quad = lane >> 4;
    const int wr = wave >> 1, wc = wave & 1;
    const int row0 = blockIdx.y * 128;
    const int col0 = blockIdx.x * 128;

    f32x4 acc[4][4] = {};

    for (int kk = 0; kk < 128; kk += 64) {
#pragma unroll
        for (int j = 0; j < 4; ++j) {
            int c = tid + j * 256;
            int r = c >> 3, c8 = (c & 7) * 8;
            bf16x8 v = {};
            if (row0 + r < M) v = *(const bf16x8*)(Abf + (size_t)(row0 + r) * 128 + kk + c8);
            *(bf16x8*)&As[r][c8] = v;
        }
#pragma unroll
        for (int j = 0; j < 4; ++j) {
            int c = tid + j * 256;
            int r = c >> 3, c8 = (c & 7) * 8;
            *(bf16x8*)&Bs[r][c8] = *(const bf16x8*)(Wt + (size_t)(col0 + r) * 128 + kk + c8);
        }
        __syncthreads();

#pragma unroll
        for (int ks = 0; ks < 2; ++ks) {
            bf16x8 a[4], b[4];
#pragma unroll
            for (int i = 0; i < 4; ++i)
                a[i] = *(const bf16x8*)&As[wr * 64 + i * 16 + lane16][ks * 32 + quad * 8];
#pragma unroll
            for (int i = 0; i < 4; ++i)
                b[i] = *(const bf16x8*)&Bs[wc * 64 + i * 16 + lane16][ks * 32 + quad * 8];
#pragma unroll
            for (int mi = 0; mi < 4; ++mi)
#pragma unroll
                for (int ni = 0; ni < 4; ++ni)
                    acc[mi][ni] = __builtin_amdgcn_mfma_f32_16x16x32_bf16(
                        a[mi], b[ni], acc[mi][ni], 0, 0, 0);
        }
        __syncthreads();
    }

    // Epilogue: C/D layout col = lane&15, row = quad*4 + reg
#pragma unroll
    for (int mi = 0; mi < 4; ++mi) {
        int rowb = row0 + wr * 64 + mi * 16 + quad * 4;
#pragma unroll
        for (int ni = 0; ni < 4; ++ni) {
            int col = col0 + wc * 64 + ni * 16 + lane16;
            float bv = bias[col];
#pragma unroll
            for (int r = 0; r < 4; ++r) {
                int gr = rowb + r;
                if (gr < M) {
                    float v = acc[mi][ni][r] + bv;
                    if (col0 < 512)       Qb[(size_t)gr * 512 + col] = f2bf(v);
                    else if (col0 < 1024) Kb[(size_t)gr * 512 + (col - 512)] = f2bf(v);
                    else if (col0 < 1536) Vb[(size_t)gr * 512 + (col - 1024)] = f2bf(v);
                    else                  Sb[(size_t)gr * 128 + (col - 1536)] = v;
                }
            }
        }
    }
}

// ---------------------------------------------------------------------------
// Attention phase A: edge-parallel alpha (fully unrolled, regs only).
// One wave per 4 edges; per edge each lane loads 16B of K[src] and Q[dst];
// reduce within 16-lane head groups. alpha stored planar [h][E].
// ---------------------------------------------------------------------------
__global__ __launch_bounds__(256) void alpha_kernel(
    const unsigned short* __restrict__ Q,    // [N][512] bf16
    const unsigned short* __restrict__ K,
    const int* __restrict__ csr_src,
    const int* __restrict__ csr_dst,
    float* __restrict__ alpha,               // [H][E]
    int E)
{
    const int lane = threadIdx.x & 63;
    const int wid = (blockIdx.x * blockDim.x + threadIdx.x) >> 6;
    const int e0 = wid * 4;
    if (e0 >= E) return;
    const int c0 = lane * 8;
    const float scale = 0.08838834764831845f;   // 1/sqrt(128)

    bf16x8 kv[4], qv[4];
#pragma unroll
    for (int j = 0; j < 4; ++j) {
        int e = e0 + j; if (e > E - 1) e = E - 1;    // clamp tail (stores guarded)
        int s = csr_src[e];
        int d = csr_dst[e];
        kv[j] = *(const bf16x8*)(K + (size_t)s * HF + c0);
        qv[j] = *(const bf16x8*)(Q + (size_t)d * HF + c0);
    }
    float p[4];
#pragma unroll
    for (int j = 0; j < 4; ++j) {
        float t = 0.f;
#pragma unroll
        for (int i = 0; i < 8; ++i)
            t += bf2f((unsigned short)kv[j][i]) * bf2f((unsigned short)qv[j][i]);
        p[j] = t;
    }
#pragma unroll
    for (int j = 0; j < 4; ++j) {
#pragma unroll
        for (int off = 1; off < 16; off <<= 1)
            p[j] += __shfl_xor(p[j], off, 64);
        p[j] *= scale;
    }
    if ((lane & 15) == 0) {
        int h = lane >> 4;
        float* ap = alpha + (size_t)h * E + e0;
        if (e0 + 4 <= E) {
            *(float4*)ap = make_float4(p[0], p[1], p[2], p[3]);
        } else {
#pragma unroll
            for (int j = 0; j < 4; ++j)
                if (e0 + j < E) ap[j] = p[j];
        }
    }
}

// ---------------------------------------------------------------------------
// Attention phase B: wave-per-node softmax + V aggregation + head-mean + skip.
// 256 thr = 4 waves = 4 nodes per block. Within a wave: 4 x 16-lane groups =
// 4 heads (uniform trip counts, zero divergence, no __syncthreads).
// Weights exp'd ONCE (lane-parallel), cached in LDS; V loop is pure
// gather+FMA at 16B/lane.
// ---------------------------------------------------------------------------
__global__ __launch_bounds__(256) void aggregate_kernel(
    const unsigned short* __restrict__ V,    // [N][512] bf16
    const float* __restrict__ S,             // [N][128]
    const float* __restrict__ alpha,         // [H][E]
    const int* __restrict__ row_ptr,
    const int* __restrict__ csr_src,
    float* __restrict__ out_f,
    unsigned short* __restrict__ out_bf,
    int relu, int N, int E)
{
    __shared__ float lds_w[16][132];         // [wave*4+head][chunk], pad 132 -> head rows hit different banks

    const int tid = threadIdx.x;
    const int wave = tid >> 6;
    const int h = (tid >> 4) & 3;
    const int lane16 = tid & 15;
    const int node = blockIdx.x * 4 + wave;
    if (node >= N) return;
    const int row = wave * 4 + h;

    const float* al = alpha + (size_t)h * E;
    const int beg = row_ptr[node];
    const int end = row_ptr[node + 1];

    // pass 1: global max over this node's alphas (head h), lane-parallel
    float m = -INFINITY;
    for (int i = beg + lane16; i < end; i += 16) m = fmaxf(m, al[i]);
#pragma unroll
    for (int off = 1; off < 16; off <<= 1) m = fmaxf(m, __shfl_xor(m, off, 64));

    float z = 0.f;
    float acc[8] = {};
    const unsigned short* Vh = V + (size_t)h * F + (size_t)lane16 * 8;

    for (int cb = beg; cb < end; cb += 128) {
        const int ce = (cb + 128 < end) ? cb + 128 : end;
        // pass 2: weights (one exp per edge, lane-parallel) -> LDS + z
        for (int i = cb + lane16; i < ce; i += 16) {
            float w = __expf(al[i] - m);
            z += w;
            lds_w[row][i - cb] = w;
        }
        // pass 3: V gather + FMA (unrolled x2, no exp, no shuffle)
        int i = cb;
        for (; i + 2 <= ce; i += 2) {
            int s0 = csr_src[i], s1 = csr_src[i + 1];
            float w0 = lds_w[row][i - cb];
            float w1 = lds_w[row][i + 1 - cb];
            bf16x8 v0 = *(const bf16x8*)(Vh + (size_t)s0 * HF);
            bf16x8 v1 = *(const bf16x8*)(Vh + (size_t)s1 * HF);
#pragma unroll
            for (int j = 0; j < 8; ++j)
                acc[j] += w0 * bf2f((unsigned short)v0[j]) + w1 * bf2f((unsigned short)v1[j]);
        }
        if (i < ce) {
            int s0 = csr_src[i];
            float w0 = lds_w[row][i - cb];
            bf16x8 v0 = *(const bf16x8*)(Vh + (size_t)s0 * HF);
#pragma unroll
            for (int j = 0; j < 8; ++j)
                acc[j] += w0 * bf2f((unsigned short)v0[j]);
        }
    }

    // z reduce within the 16-lane group; normalize
#pragma unroll
    for (int off = 1; off < 16; off <<= 1) z += __shfl_xor(z, off, 64);
    float inv = (z > 0.f) ? 1.f / z : 0.f;
#pragma unroll
    for (int j = 0; j < 8; ++j) acc[j] *= inv;

    // head-mean: butterfly across the 4 groups of this wave
#pragma unroll
    for (int j = 0; j < 8; ++j) {
        acc[j] += __shfl_xor(acc[j], 16, 64);
        acc[j] += __shfl_xor(acc[j], 32, 64);
    }

    // epilogue by group 0 (lanes 0..15): 8 channels per lane
    if (h == 0) {
        const float* Sp = S + (size_t)node * F + lane16 * 8;
        float4 s0 = *(const float4*)(Sp);
        float4 s1 = *(const float4*)(Sp + 4);
        float o[8];
        o[0] = 0.25f * acc[0] + s0.x; o[1] = 0.25f * acc[1] + s0.y;
        o[2] = 0.25f * acc[2] + s0.z; o[3] = 0.25f * acc[3] + s0.w;
        o[4] = 0.25f * acc[4] + s1.x; o[5] = 0.25f * acc[5] + s1.y;
        o[6] = 0.25f * acc[6] + s1.z; o[7] = 0.25f * acc[7] + s1.w;
        if (relu) {
#pragma unroll
            for (int j = 0; j < 8; ++j) o[j] = fmaxf(o[j], 0.f);
        }
        if (out_f) {
            float* op = out_f + (size_t)node * F + lane16 * 8;
            *(float4*)op = make_float4(o[0], o[1], o[2], o[3]);
            *(float4*)(op + 4) = make_float4(o[4], o[5], o[6], o[7]);
        }
        if (out_bf) {
            ushort4 b0, b1;
            b0.x = f2bf(o[0]); b0.y = f2bf(o[1]); b0.z = f2bf(o[2]); b0.w = f2bf(o[3]);
            b1.x = f2bf(o[4]); b1.y = f2bf(o[5]); b1.z = f2bf(o[6]); b1.w = f2bf(o[7]);
            unsigned short* op = out_bf + (size_t)node * F + lane16 * 8;
            *(ushort4*)op = b0;
            *(ushort4*)(op + 4) = b1;
        }
    }
}

// ---------------------------------------------------------------------------
// Launch
// ---------------------------------------------------------------------------
extern "C" void kernel_launch(void* const* d_in, const int* in_sizes, int n_in,
                              void* d_out, int out_size, void* d_ws, size_t ws_size,
                              hipStream_t stream) {
    const float* x     = (const float*)d_in[0];
    const int*   ei    = (const int*)d_in[1];
    const float* Wq    = (const float*)d_in[2];
    const float* bq    = (const float*)d_in[3];
    const float* Wk    = (const float*)d_in[4];
    const float* bk    = (const float*)d_in[5];
    const float* Wv    = (const float*)d_in[6];
    const float* bv    = (const float*)d_in[7];
    const float* Wskip = (const float*)d_in[8];
    const float* bskip = (const float*)d_in[9];
    float* out = (float*)d_out;

    const int N = in_sizes[0] / F;       // 10000
    const int E = in_sizes[1] / 2;       // 160000

    const int* src = ei;
    const int* dst = ei + E;

    // Workspace layout
    char* p = (char*)d_ws;
    float* Sb    = (float*)p;                 p += (size_t)N * F * sizeof(float);
    float* biasP = (float*)p;                 p += (size_t)LAYERS * NC * sizeof(float);
    float* alphaB = (float*)p;                p += (size_t)H * E * sizeof(float);
    unsigned short* h_bf = (unsigned short*)p; p += (size_t)N * F * sizeof(unsigned short);
    unsigned short* Qb   = (unsigned short*)p; p += (size_t)N * HF * sizeof(unsigned short);
    unsigned short* Kb   = (unsigned short*)p; p += (size_t)N * HF * sizeof(unsigned short);
    unsigned short* Vb   = (unsigned short*)p; p += (size_t)N * HF * sizeof(unsigned short);
    unsigned short* WtP  = (unsigned short*)p; p += (size_t)LAYERS * NC * 128 * sizeof(unsigned short);
    int* deg     = (int*)p;                   p += (size_t)N * sizeof(int);
    int* cursor  = (int*)p;                   p += (size_t)N * sizeof(int);
    int* row_ptr = (int*)p;                   p += (size_t)(N + 1) * sizeof(int);
    int* csr_src = (int*)p;                   p += (size_t)E * sizeof(int);
    int* csr_dst = (int*)p;

    // --- CSR build
    hipMemsetAsync(deg, 0, 2 * (size_t)N * sizeof(int), stream);  // deg + cursor
    {
        int blocks = (E + 255) / 256;
        hist_kernel<<<blocks, 256, 0, stream>>>(dst, deg, E);
        scan_kernel<<<1, 1024, 0, stream>>>(deg, row_ptr, N);
        scatter_kernel<<<blocks, 256, 0, stream>>>(src, dst, row_ptr, cursor, csr_src, csr_dst, E);
    }

    // --- One-time packs/converts
    convert_kernel<<<(N * F / 4 + 255) / 256, 256, 0, stream>>>(x, h_bf, N * F / 4);
    {
        dim3 g(NC / 32, 128 / 32, LAYERS);
        pack_w_kernel<<<g, 256, 0, stream>>>(Wq, Wk, Wv, Wskip, WtP);
    }
    pack_b_kernel<<<(LAYERS * NC + 255) / 256, 256, 0, stream>>>(bq, bk, bv, bskip, biasP);

    const int rowBlocks = (N + 127) / 128;
    const int alphaBlocks = (E + 15) / 16;   // 4 waves x 4 edges per block
    const int aggBlocks = (N + 3) / 4;       // 4 waves = 4 nodes per block

    for (int l = 0; l < LAYERS; ++l) {
        dim3 grid(NC / 128, rowBlocks);
        gemm_mfma<<<grid, 256, 0, stream>>>(h_bf,
                                            WtP + (size_t)l * NC * 128,
                                            biasP + (size_t)l * NC,
                                            Qb, Kb, Vb, Sb, N);

        alpha_kernel<<<alphaBlocks, 256, 0, stream>>>(Qb, Kb, csr_src, csr_dst,
                                                      alphaB, E);

        float* out_f = nullptr;
        unsigned short* out_bf = nullptr;
        int relu;
        if (l == LAYERS - 1) { out_f = out; relu = 0; }
        else { out_bf = h_bf; relu = 1; }

        aggregate_kernel<<<aggBlocks, 256, 0, stream>>>(Vb, Sb, alphaB, row_ptr, csr_src,
                                                        out_f, out_bf, relu, N, E);
    }
}

// Round 6
// 442.089 us; speedup vs baseline: 4.3924x; 1.0013x over previous
//
#include <hip/hip_runtime.h>
#include <math.h>

static constexpr int F  = 128;    // channels per head
static constexpr int H  = 4;      // heads
static constexpr int HF = 512;    // H*F
static constexpr int NC = 1664;   // packed GEMM cols: Q(512)|K(512)|V(512)|S(128)
static constexpr int LAYERS = 4;

typedef __attribute__((ext_vector_type(8))) short bf16x8;   // 8 bf16 (4 VGPRs)
typedef __attribute__((ext_vector_type(4))) float f32x4;

__device__ __forceinline__ unsigned short f2bf(float f) {
    union { float f; unsigned u; } v; v.f = f;
    unsigned r = (v.u + 0x7FFFu + ((v.u >> 16) & 1u)) >> 16;  // RNE
    return (unsigned short)r;
}
__device__ __forceinline__ float bf2f(unsigned short b) {
    union { unsigned u; float f; } v; v.u = ((unsigned)b) << 16;
    return v.f;
}

// ---------------------------------------------------------------------------
// CSR build (counting sort of edges by dst)
// ---------------------------------------------------------------------------
__global__ void hist_kernel(const int* __restrict__ dst, int* __restrict__ deg, int E) {
    int e = blockIdx.x * blockDim.x + threadIdx.x;
    if (e < E) atomicAdd(&deg[dst[e]], 1);
}

// 1024-thread wave-shuffle scan (16 waves), 3 barriers per chunk
__global__ void scan_kernel(const int* __restrict__ deg, int* __restrict__ row_ptr, int n) {
    __shared__ int wsum[16];
    __shared__ int carry_s, wtot_s;
    const int tid = threadIdx.x;
    const int lane = tid & 63;
    const int wid = tid >> 6;
    if (tid == 0) { carry_s = 0; row_ptr[0] = 0; }
    __syncthreads();
    for (int base = 0; base < n; base += 1024) {
        int i = base + tid;
        int x = (i < n) ? deg[i] : 0;
#pragma unroll
        for (int off = 1; off < 64; off <<= 1) {
            int t = __shfl_up(x, off, 64);
            if (lane >= off) x += t;
        }
        if (lane == 63) wsum[wid] = x;
        __syncthreads();
        if (tid == 0) {
            int s = 0;
#pragma unroll
            for (int j = 0; j < 16; ++j) { int t = wsum[j]; wsum[j] = s; s += t; }
            wtot_s = s;
        }
        __syncthreads();
        int incl = x + wsum[wid] + carry_s;
        if (i < n) row_ptr[i + 1] = incl;
        __syncthreads();
        if (tid == 0) carry_s += wtot_s;
        __syncthreads();
    }
}

__global__ void scatter_kernel(const int* __restrict__ src, const int* __restrict__ dst,
                               const int* __restrict__ row_ptr, int* __restrict__ cursor,
                               int* __restrict__ csr_src, int E) {
    int e = blockIdx.x * blockDim.x + threadIdx.x;
    if (e < E) {
        int d = dst[e];
        int pos = atomicAdd(&cursor[d], 1);
        csr_src[row_ptr[d] + pos] = src[e];
    }
}

// ---------------------------------------------------------------------------
// fp32 -> bf16 convert (x -> h_bf at layer 0)
// ---------------------------------------------------------------------------
__global__ void convert_kernel(const float* __restrict__ in, unsigned short* __restrict__ out, int n4) {
    int i = blockIdx.x * blockDim.x + threadIdx.x;
    if (i < n4) {
        float4 v = *(const float4*)(in + (size_t)i * 4);
        ushort4 o;
        o.x = f2bf(v.x); o.y = f2bf(v.y); o.z = f2bf(v.z); o.w = f2bf(v.w);
        *(ushort4*)(out + (size_t)i * 4) = o;
    }
}

// ---------------------------------------------------------------------------
// Weight pack via LDS-tiled transpose: Wt[l][n][k] (bf16) from W*[l][k][n] (fp32)
// ---------------------------------------------------------------------------
__global__ __launch_bounds__(256) void pack_w_kernel(
    const float* __restrict__ Wq, const float* __restrict__ Wk,
    const float* __restrict__ Wv, const float* __restrict__ Ws,
    unsigned short* __restrict__ Wt)
{
    __shared__ unsigned short t[32][33];
    const int l  = blockIdx.z;
    const int k0 = blockIdx.y * 32;
    const int n0 = blockIdx.x * 32;
    const int cx = threadIdx.x & 31;
    const int ry = threadIdx.x >> 5;   // 0..7
#pragma unroll
    for (int rr = 0; rr < 32; rr += 8) {
        int k = k0 + ry + rr;
        int n = n0 + cx;
        float v;
        if (n < 512)       v = Wq[(size_t)l * 65536 + (size_t)k * 512 + n];
        else if (n < 1024) v = Wk[(size_t)l * 65536 + (size_t)k * 512 + (n - 512)];
        else if (n < 1536) v = Wv[(size_t)l * 65536 + (size_t)k * 512 + (n - 1024)];
        else               v = Ws[(size_t)l * 16384 + (size_t)k * 128 + (n - 1536)];
        t[ry + rr][cx] = f2bf(v);
    }
    __syncthreads();
#pragma unroll
    for (int rr = 0; rr < 32; rr += 8) {
        int n = n0 + ry + rr;
        int k = k0 + cx;
        Wt[(size_t)l * NC * 128 + (size_t)n * 128 + k] = t[cx][ry + rr];
    }
}

__global__ void pack_b_kernel(const float* __restrict__ bq, const float* __restrict__ bk,
                              const float* __restrict__ bv, const float* __restrict__ bs,
                              float* __restrict__ biasP) {
    int idx = blockIdx.x * blockDim.x + threadIdx.x;   // l*NC + n
    if (idx >= LAYERS * NC) return;
    int n = idx % NC;
    int l = idx / NC;
    float v;
    if (n < 512)       v = bq[(size_t)l * 512 + n];
    else if (n < 1024) v = bk[(size_t)l * 512 + (n - 512)];
    else if (n < 1536) v = bv[(size_t)l * 512 + (n - 1024)];
    else               v = bs[(size_t)l * 128 + (n - 1536)];
    biasP[idx] = v;
}

// ---------------------------------------------------------------------------
// Fused bf16 MFMA GEMM: C[M x 1664] = A[M x 128] @ Wt^T + bias
// ---------------------------------------------------------------------------
__global__ __launch_bounds__(256) void gemm_mfma(
    const unsigned short* __restrict__ Abf,   // [M][128] bf16
    const unsigned short* __restrict__ Wt,    // [NC][128] bf16 (layer base)
    const float* __restrict__ bias,           // [NC]
    unsigned short* __restrict__ Qb,          // [M][512] bf16
    unsigned short* __restrict__ Kb,
    unsigned short* __restrict__ Vb,
    float* __restrict__ Sb,                   // [M][128] fp32
    int M)
{
    __shared__ unsigned short As[128][72];    // 64+8 pad
    __shared__ unsigned short Bs[128][72];

    const int tid = threadIdx.x;
    const int wave = tid >> 6, lane = tid & 63;
    const int lane16 = lane & 15, quad = lane >> 4;
    const int wr = wave >> 1, wc = wave & 1;
    const int row0 = blockIdx.y * 128;
    const int col0 = blockIdx.x * 128;

    f32x4 acc[4][4] = {};

    for (int kk = 0; kk < 128; kk += 64) {
#pragma unroll
        for (int j = 0; j < 4; ++j) {
            int c = tid + j * 256;
            int r = c >> 3, c8 = (c & 7) * 8;
            bf16x8 v = {};
            if (row0 + r < M) v = *(const bf16x8*)(Abf + (size_t)(row0 + r) * 128 + kk + c8);
            *(bf16x8*)&As[r][c8] = v;
        }
#pragma unroll
        for (int j = 0; j < 4; ++j) {
            int c = tid + j * 256;
            int r = c >> 3, c8 = (c & 7) * 8;
            *(bf16x8*)&Bs[r][c8] = *(const bf16x8*)(Wt + (size_t)(col0 + r) * 128 + kk + c8);
        }
        __syncthreads();

#pragma unroll
        for (int ks = 0; ks < 2; ++ks) {
            bf16x8 a[4], b[4];
#pragma unroll
            for (int i = 0; i < 4; ++i)
                a[i] = *(const bf16x8*)&As[wr * 64 + i * 16 + lane16][ks * 32 + quad * 8];
#pragma unroll
            for (int i = 0; i < 4; ++i)
                b[i] = *(const bf16x8*)&Bs[wc * 64 + i * 16 + lane16][ks * 32 + quad * 8];
#pragma unroll
            for (int mi = 0; mi < 4; ++mi)
#pragma unroll
                for (int ni = 0; ni < 4; ++ni)
                    acc[mi][ni] = __builtin_amdgcn_mfma_f32_16x16x32_bf16(
                        a[mi], b[ni], acc[mi][ni], 0, 0, 0);
        }
        __syncthreads();
    }

    // Epilogue: C/D layout col = lane&15, row = quad*4 + reg
#pragma unroll
    for (int mi = 0; mi < 4; ++mi) {
        int rowb = row0 + wr * 64 + mi * 16 + quad * 4;
#pragma unroll
        for (int ni = 0; ni < 4; ++ni) {
            int col = col0 + wc * 64 + ni * 16 + lane16;
            float bv = bias[col];
#pragma unroll
            for (int r = 0; r < 4; ++r) {
                int gr = rowb + r;
                if (gr < M) {
                    float v = acc[mi][ni][r] + bv;
                    if (col0 < 512)       Qb[(size_t)gr * 512 + col] = f2bf(v);
                    else if (col0 < 1024) Kb[(size_t)gr * 512 + (col - 512)] = f2bf(v);
                    else if (col0 < 1536) Vb[(size_t)gr * 512 + (col - 1024)] = f2bf(v);
                    else                  Sb[(size_t)gr * 128 + (col - 1536)] = v;
                }
            }
        }
    }
}

// ---------------------------------------------------------------------------
// FUSED attention: one wave = one node; 4 x 16-lane groups = 4 heads.
// Q in registers (scale folded). Per chunk of <=128 edges:
//   phase A: K-row gather (1KB coalesced per edge, whole wave) -> alpha in LDS
//   chunk max + flash-style online rescale of (z, acc)
//   phase B: weights = exp(alpha-m), lane-parallel, back into LDS
//   phase C: V-row gather + FMA with LDS-broadcast weight
// LDS rows are wave-private -> NO __syncthreads anywhere.
// ---------------------------------------------------------------------------
__global__ __launch_bounds__(256) void attn_fused(
    const unsigned short* __restrict__ Q,    // [N][512] bf16
    const unsigned short* __restrict__ K,
    const unsigned short* __restrict__ V,
    const float* __restrict__ S,             // [N][128]
    const int* __restrict__ row_ptr,
    const int* __restrict__ csr_src,
    float* __restrict__ out_f,
    unsigned short* __restrict__ out_bf,
    int relu, int N)
{
    __shared__ float lds_a[16][132];         // [wave*4+head][chunk idx]

    const int tid = threadIdx.x;
    const int wave = tid >> 6;
    const int lane = tid & 63;
    const int h = (tid >> 4) & 3;
    const int lane16 = tid & 15;
    const int node = blockIdx.x * 4 + wave;
    if (node >= N) return;
    const int row = (wave << 2) | h;
    const float scale = 0.08838834764831845f;   // 1/sqrt(128)

    // Q row in registers, pre-scaled (lane covers channels lane*8 .. lane*8+7)
    bf16x8 qb = *(const bf16x8*)(Q + (size_t)node * HF + (size_t)lane * 8);
    float qf[8];
#pragma unroll
    for (int j = 0; j < 8; ++j) qf[j] = bf2f((unsigned short)qb[j]) * scale;

    const unsigned short* Kl = K + (size_t)lane * 8;
    const unsigned short* Vl = V + (size_t)lane * 8;

    const int beg = row_ptr[node];
    const int end = row_ptr[node + 1];

    float m = -INFINITY, z = 0.f;
    float acc[8] = {};

    for (int cb = beg; cb < end; cb += 128) {
        const int ce = (cb + 128 < end) ? cb + 128 : end;

        // --- phase A: alphas for this chunk -> LDS
        int i = cb;
        for (; i + 2 <= ce; i += 2) {
            int s0 = csr_src[i], s1 = csr_src[i + 1];
            bf16x8 k0 = *(const bf16x8*)(Kl + (size_t)s0 * HF);
            bf16x8 k1 = *(const bf16x8*)(Kl + (size_t)s1 * HF);
            float p0 = 0.f, p1 = 0.f;
#pragma unroll
            for (int j = 0; j < 8; ++j) {
                p0 += qf[j] * bf2f((unsigned short)k0[j]);
                p1 += qf[j] * bf2f((unsigned short)k1[j]);
            }
#pragma unroll
            for (int off = 1; off < 16; off <<= 1) {
                p0 += __shfl_xor(p0, off, 64);
                p1 += __shfl_xor(p1, off, 64);
            }
            if (lane16 == 0) {
                lds_a[row][i - cb] = p0;
                lds_a[row][i + 1 - cb] = p1;
            }
        }
        if (i < ce) {
            int s0 = csr_src[i];
            bf16x8 k0 = *(const bf16x8*)(Kl + (size_t)s0 * HF);
            float p0 = 0.f;
#pragma unroll
            for (int j = 0; j < 8; ++j) p0 += qf[j] * bf2f((unsigned short)k0[j]);
#pragma unroll
            for (int off = 1; off < 16; off <<= 1) p0 += __shfl_xor(p0, off, 64);
            if (lane16 == 0) lds_a[row][i - cb] = p0;
        }

        // --- chunk max + online rescale
        float mc = -INFINITY;
        for (int t = lane16; t < ce - cb; t += 16) mc = fmaxf(mc, lds_a[row][t]);
#pragma unroll
        for (int off = 1; off < 16; off <<= 1) mc = fmaxf(mc, __shfl_xor(mc, off, 64));
        float mn = fmaxf(m, mc);
        float rs = __expf(m - mn);       // 0 on first chunk (m = -inf)
        z *= rs;
#pragma unroll
        for (int j = 0; j < 8; ++j) acc[j] *= rs;
        m = mn;

        // --- phase B: weights (one exp per edge, lane-parallel)
        for (int t = lane16; t < ce - cb; t += 16) {
            float w = __expf(lds_a[row][t] - m);
            z += w;
            lds_a[row][t] = w;
        }

        // --- phase C: V gather + FMA
        i = cb;
        for (; i + 2 <= ce; i += 2) {
            int s0 = csr_src[i], s1 = csr_src[i + 1];
            float w0 = lds_a[row][i - cb];
            float w1 = lds_a[row][i + 1 - cb];
            bf16x8 v0 = *(const bf16x8*)(Vl + (size_t)s0 * HF);
            bf16x8 v1 = *(const bf16x8*)(Vl + (size_t)s1 * HF);
#pragma unroll
            for (int j = 0; j < 8; ++j)
                acc[j] += w0 * bf2f((unsigned short)v0[j]) + w1 * bf2f((unsigned short)v1[j]);
        }
        if (i < ce) {
            int s0 = csr_src[i];
            float w0 = lds_a[row][i - cb];
            bf16x8 v0 = *(const bf16x8*)(Vl + (size_t)s0 * HF);
#pragma unroll
            for (int j = 0; j < 8; ++j)
                acc[j] += w0 * bf2f((unsigned short)v0[j]);
        }
    }

    // z reduce within the 16-lane group; normalize
#pragma unroll
    for (int off = 1; off < 16; off <<= 1) z += __shfl_xor(z, off, 64);
    float inv = (z > 0.f) ? 1.f / z : 0.f;
#pragma unroll
    for (int j = 0; j < 8; ++j) acc[j] *= inv;

    // head-mean: butterfly across the 4 groups of this wave
#pragma unroll
    for (int j = 0; j < 8; ++j) {
        acc[j] += __shfl_xor(acc[j], 16, 64);
        acc[j] += __shfl_xor(acc[j], 32, 64);
    }

    // epilogue by group 0 (lanes 0..15): 8 channels per lane
    if (h == 0) {
        const float* Sp = S + (size_t)node * F + lane16 * 8;
        float4 s0 = *(const float4*)(Sp);
        float4 s1 = *(const float4*)(Sp + 4);
        float o[8];
        o[0] = 0.25f * acc[0] + s0.x; o[1] = 0.25f * acc[1] + s0.y;
        o[2] = 0.25f * acc[2] + s0.z; o[3] = 0.25f * acc[3] + s0.w;
        o[4] = 0.25f * acc[4] + s1.x; o[5] = 0.25f * acc[5] + s1.y;
        o[6] = 0.25f * acc[6] + s1.z; o[7] = 0.25f * acc[7] + s1.w;
        if (relu) {
#pragma unroll
            for (int j = 0; j < 8; ++j) o[j] = fmaxf(o[j], 0.f);
        }
        if (out_f) {
            float* op = out_f + (size_t)node * F + lane16 * 8;
            *(float4*)op = make_float4(o[0], o[1], o[2], o[3]);
            *(float4*)(op + 4) = make_float4(o[4], o[5], o[6], o[7]);
        }
        if (out_bf) {
            ushort4 b0, b1;
            b0.x = f2bf(o[0]); b0.y = f2bf(o[1]); b0.z = f2bf(o[2]); b0.w = f2bf(o[3]);
            b1.x = f2bf(o[4]); b1.y = f2bf(o[5]); b1.z = f2bf(o[6]); b1.w = f2bf(o[7]);
            unsigned short* op = out_bf + (size_t)node * F + lane16 * 8;
            *(ushort4*)op = b0;
            *(ushort4*)(op + 4) = b1;
        }
    }
}

// ---------------------------------------------------------------------------
// Launch
// ---------------------------------------------------------------------------
extern "C" void kernel_launch(void* const* d_in, const int* in_sizes, int n_in,
                              void* d_out, int out_size, void* d_ws, size_t ws_size,
                              hipStream_t stream) {
    const float* x     = (const float*)d_in[0];
    const int*   ei    = (const int*)d_in[1];
    const float* Wq    = (const float*)d_in[2];
    const float* bq    = (const float*)d_in[3];
    const float* Wk    = (const float*)d_in[4];
    const float* bk    = (const float*)d_in[5];
    const float* Wv    = (const float*)d_in[6];
    const float* bv    = (const float*)d_in[7];
    const float* Wskip = (const float*)d_in[8];
    const float* bskip = (const float*)d_in[9];
    float* out = (float*)d_out;

    const int N = in_sizes[0] / F;       // 10000
    const int E = in_sizes[1] / 2;       // 160000

    const int* src = ei;
    const int* dst = ei + E;

    // Workspace layout
    char* p = (char*)d_ws;
    float* Sb    = (float*)p;                 p += (size_t)N * F * sizeof(float);
    float* biasP = (float*)p;                 p += (size_t)LAYERS * NC * sizeof(float);
    unsigned short* h_bf = (unsigned short*)p; p += (size_t)N * F * sizeof(unsigned short);
    unsigned short* Qb   = (unsigned short*)p; p += (size_t)N * HF * sizeof(unsigned short);
    unsigned short* Kb   = (unsigned short*)p; p += (size_t)N * HF * sizeof(unsigned short);
    unsigned short* Vb   = (unsigned short*)p; p += (size_t)N * HF * sizeof(unsigned short);
    unsigned short* WtP  = (unsigned short*)p; p += (size_t)LAYERS * NC * 128 * sizeof(unsigned short);
    int* deg     = (int*)p;                   p += (size_t)N * sizeof(int);
    int* cursor  = (int*)p;                   p += (size_t)N * sizeof(int);
    int* row_ptr = (int*)p;                   p += (size_t)(N + 1) * sizeof(int);
    int* csr_src = (int*)p;

    // --- CSR build
    hipMemsetAsync(deg, 0, 2 * (size_t)N * sizeof(int), stream);  // deg + cursor
    {
        int blocks = (E + 255) / 256;
        hist_kernel<<<blocks, 256, 0, stream>>>(dst, deg, E);
        scan_kernel<<<1, 1024, 0, stream>>>(deg, row_ptr, N);
        scatter_kernel<<<blocks, 256, 0, stream>>>(src, dst, row_ptr, cursor, csr_src, E);
    }

    // --- One-time packs/converts
    convert_kernel<<<(N * F / 4 + 255) / 256, 256, 0, stream>>>(x, h_bf, N * F / 4);
    {
        dim3 g(NC / 32, 128 / 32, LAYERS);
        pack_w_kernel<<<g, 256, 0, stream>>>(Wq, Wk, Wv, Wskip, WtP);
    }
    pack_b_kernel<<<(LAYERS * NC + 255) / 256, 256, 0, stream>>>(bq, bk, bv, bskip, biasP);

    const int rowBlocks = (N + 127) / 128;
    const int attnBlocks = (N + 3) / 4;      // 4 waves = 4 nodes per block

    for (int l = 0; l < LAYERS; ++l) {
        dim3 grid(NC / 128, rowBlocks);
        gemm_mfma<<<grid, 256, 0, stream>>>(h_bf,
                                            WtP + (size_t)l * NC * 128,
                                            biasP + (size_t)l * NC,
                                            Qb, Kb, Vb, Sb, N);

        float* out_f = nullptr;
        unsigned short* out_bf = nullptr;
        int relu;
        if (l == LAYERS - 1) { out_f = out; relu = 0; }
        else { out_bf = h_bf; relu = 1; }

        attn_fused<<<attnBlocks, 256, 0, stream>>>(Qb, Kb, Vb, Sb, row_ptr, csr_src,
                                                   out_f, out_bf, relu, N);
    }
}

// Round 7
// 386.541 us; speedup vs baseline: 5.0237x; 1.1437x over previous
//
#include <hip/hip_runtime.h>
#include <math.h>

static constexpr int F  = 128;    // channels per head / input dim
static constexpr int H  = 4;      // heads
static constexpr int HF = 512;    // H*F
static constexpr int NCP = 640;   // pre-GEMM cols: q-tilde(512) | S(128)
static constexpr int LAYERS = 4;

typedef __attribute__((ext_vector_type(8))) short bf16x8;   // 8 bf16 (4 VGPRs)
typedef __attribute__((ext_vector_type(4))) float f32x4;

__device__ __forceinline__ unsigned short f2bf(float f) {
    union { float f; unsigned u; } v; v.f = f;
    unsigned r = (v.u + 0x7FFFu + ((v.u >> 16) & 1u)) >> 16;  // RNE
    return (unsigned short)r;
}
__device__ __forceinline__ float bf2f(unsigned short b) {
    union { unsigned u; float f; } v; v.u = ((unsigned)b) << 16;
    return v.f;
}

// ---------------------------------------------------------------------------
// CSR build (counting sort of edges by dst)
// ---------------------------------------------------------------------------
__global__ void hist_kernel(const int* __restrict__ dst, int* __restrict__ deg, int E) {
    int e = blockIdx.x * blockDim.x + threadIdx.x;
    if (e < E) atomicAdd(&deg[dst[e]], 1);
}

__global__ void scan_kernel(const int* __restrict__ deg, int* __restrict__ row_ptr, int n) {
    __shared__ int wsum[16];
    __shared__ int carry_s, wtot_s;
    const int tid = threadIdx.x;
    const int lane = tid & 63;
    const int wid = tid >> 6;
    if (tid == 0) { carry_s = 0; row_ptr[0] = 0; }
    __syncthreads();
    for (int base = 0; base < n; base += 1024) {
        int i = base + tid;
        int x = (i < n) ? deg[i] : 0;
#pragma unroll
        for (int off = 1; off < 64; off <<= 1) {
            int t = __shfl_up(x, off, 64);
            if (lane >= off) x += t;
        }
        if (lane == 63) wsum[wid] = x;
        __syncthreads();
        if (tid == 0) {
            int s = 0;
#pragma unroll
            for (int j = 0; j < 16; ++j) { int t = wsum[j]; wsum[j] = s; s += t; }
            wtot_s = s;
        }
        __syncthreads();
        int incl = x + wsum[wid] + carry_s;
        if (i < n) row_ptr[i + 1] = incl;
        __syncthreads();
        if (tid == 0) carry_s += wtot_s;
        __syncthreads();
    }
}

__global__ void scatter_kernel(const int* __restrict__ src, const int* __restrict__ dst,
                               const int* __restrict__ row_ptr, int* __restrict__ cursor,
                               int* __restrict__ csr_src, int E) {
    int e = blockIdx.x * blockDim.x + threadIdx.x;
    if (e < E) {
        int d = dst[e];
        int pos = atomicAdd(&cursor[d], 1);
        csr_src[row_ptr[d] + pos] = src[e];
    }
}

// ---------------------------------------------------------------------------
// fp32 -> bf16 convert (x -> h_bf at layer 0)
// ---------------------------------------------------------------------------
__global__ void convert_kernel(const float* __restrict__ in, unsigned short* __restrict__ out, int n4) {
    int i = blockIdx.x * blockDim.x + threadIdx.x;
    if (i < n4) {
        float4 v = *(const float4*)(in + (size_t)i * 4);
        ushort4 o;
        o.x = f2bf(v.x); o.y = f2bf(v.y); o.z = f2bf(v.z); o.w = f2bf(v.w);
        *(ushort4*)(out + (size_t)i * 4) = o;
    }
}

// ---------------------------------------------------------------------------
// Wqk composite: Bpre[l][n=h*128+c][k] = scale * sum_j Wq[l][k][h*128+j]*Wk[l][c][h*128+j]
// One-time, fp32 accum, 64x64 tiles. grid (2,2,L*H), block 256.
// ---------------------------------------------------------------------------
__global__ __launch_bounds__(256) void wqk_kernel(
    const float* __restrict__ Wq, const float* __restrict__ Wk,
    unsigned short* __restrict__ Bpre, float scale)
{
    __shared__ float As[64][33];   // Wk rows (c)
    __shared__ float Bs[64][33];   // Wq rows (k)
    const int lh = blockIdx.z;
    const int l = lh >> 2, h = lh & 3;
    const int c0 = blockIdx.y * 64;
    const int k0 = blockIdx.x * 64;
    const float* Ab = Wk + (size_t)l * 65536 + h * 128;
    const float* Bb = Wq + (size_t)l * 65536 + h * 128;
    const int tid = threadIdx.x;
    const int tx = tid & 15, ty = tid >> 4;

    float acc[4][4] = {};
    for (int jj = 0; jj < 128; jj += 32) {
#pragma unroll
        for (int rep = 0; rep < 2; ++rep) {
            int f = tid + rep * 256;
            int r = f >> 3, j4 = (f & 7) * 4;
            float4 a = *(const float4*)(Ab + (size_t)(c0 + r) * 512 + jj + j4);
            As[r][j4 + 0] = a.x; As[r][j4 + 1] = a.y; As[r][j4 + 2] = a.z; As[r][j4 + 3] = a.w;
            float4 b = *(const float4*)(Bb + (size_t)(k0 + r) * 512 + jj + j4);
            Bs[r][j4 + 0] = b.x; Bs[r][j4 + 1] = b.y; Bs[r][j4 + 2] = b.z; Bs[r][j4 + 3] = b.w;
        }
        __syncthreads();
#pragma unroll
        for (int j = 0; j < 32; ++j) {
            float a0 = As[ty * 4 + 0][j], a1 = As[ty * 4 + 1][j];
            float a2 = As[ty * 4 + 2][j], a3 = As[ty * 4 + 3][j];
            float b0 = Bs[tx * 4 + 0][j], b1 = Bs[tx * 4 + 1][j];
            float b2 = Bs[tx * 4 + 2][j], b3 = Bs[tx * 4 + 3][j];
            acc[0][0] += a0 * b0; acc[0][1] += a0 * b1; acc[0][2] += a0 * b2; acc[0][3] += a0 * b3;
            acc[1][0] += a1 * b0; acc[1][1] += a1 * b1; acc[1][2] += a1 * b2; acc[1][3] += a1 * b3;
            acc[2][0] += a2 * b0; acc[2][1] += a2 * b1; acc[2][2] += a2 * b2; acc[2][3] += a2 * b3;
            acc[3][0] += a3 * b0; acc[3][1] += a3 * b1; acc[3][2] += a3 * b2; acc[3][3] += a3 * b3;
        }
        __syncthreads();
    }
#pragma unroll
    for (int i = 0; i < 4; ++i)
#pragma unroll
        for (int t = 0; t < 4; ++t) {
            int c = c0 + ty * 4 + i;
            int k = k0 + tx * 4 + t;
            Bpre[(size_t)l * NCP * 128 + (size_t)(h * 128 + c) * 128 + k] = f2bf(scale * acc[i][t]);
        }
}

// ---------------------------------------------------------------------------
// Pack skip weights into Bpre cols 512..639: Bpre[l][512+n][k] = Ws[l][k][n]
// grid (4 ktiles, 4 ntiles, L)
// ---------------------------------------------------------------------------
__global__ __launch_bounds__(256) void pack_ws_kernel(
    const float* __restrict__ Ws, unsigned short* __restrict__ Bpre)
{
    __shared__ unsigned short t[32][33];
    const int l  = blockIdx.z;
    const int k0 = blockIdx.x * 32;
    const int n0 = blockIdx.y * 32;
    const int cx = threadIdx.x & 31;
    const int ry = threadIdx.x >> 5;
#pragma unroll
    for (int rr = 0; rr < 32; rr += 8) {
        int k = k0 + ry + rr;
        t[ry + rr][cx] = f2bf(Ws[(size_t)l * 16384 + (size_t)k * 128 + n0 + cx]);
    }
    __syncthreads();
#pragma unroll
    for (int rr = 0; rr < 32; rr += 8) {
        int n = n0 + ry + rr;
        Bpre[(size_t)l * NCP * 128 + (size_t)(512 + n) * 128 + k0 + cx] = t[cx][ry + rr];
    }
}

// ---------------------------------------------------------------------------
// Pack post weights: Bpost[l][c_out][h*128+c_in] = 0.25*Wv[l][c_in][h*128+c_out]
// grid (4 ci-tiles, 4 co-tiles, L*H)
// ---------------------------------------------------------------------------
__global__ __launch_bounds__(256) void pack_bpost_kernel(
    const float* __restrict__ Wv, unsigned short* __restrict__ Bpost)
{
    __shared__ unsigned short t[32][33];
    const int lh = blockIdx.z;
    const int l = lh >> 2, h = lh & 3;
    const int ci0 = blockIdx.x * 32;
    const int co0 = blockIdx.y * 32;
    const int cx = threadIdx.x & 31;
    const int ry = threadIdx.x >> 5;
#pragma unroll
    for (int rr = 0; rr < 32; rr += 8) {
        int ci = ci0 + ry + rr;
        t[ry + rr][cx] = f2bf(0.25f * Wv[(size_t)l * 65536 + (size_t)ci * 512 + h * 128 + co0 + cx]);
    }
    __syncthreads();
#pragma unroll
    for (int rr = 0; rr < 32; rr += 8) {
        int co = co0 + ry + rr;
        Bpost[(size_t)l * 65536 + (size_t)co * 512 + h * 128 + ci0 + cx] = t[cx][ry + rr];
    }
}

// ---------------------------------------------------------------------------
// Biases (one-time, tiny). biasPre[l][n<512] = scale * bq_h . Wk_h[c,:];
// biasPre[l][512+c] = bs[c]; biasPost[l][c] = 0.25 * sum_h bv[h*128+c]
// ---------------------------------------------------------------------------
__global__ void bias_kernel(const float* __restrict__ bq, const float* __restrict__ Wk,
                            const float* __restrict__ bs, const float* __restrict__ bv,
                            float* __restrict__ biasPre, float* __restrict__ biasPost,
                            float scale)
{
    const int l = blockIdx.x;
    for (int n = threadIdx.x; n < NCP; n += blockDim.x) {
        float v;
        if (n < 512) {
            int h = n >> 7, c = n & 127;
            float s = 0.f;
            for (int j = 0; j < 128; ++j)
                s += bq[(size_t)l * 512 + h * 128 + j] * Wk[(size_t)l * 65536 + (size_t)c * 512 + h * 128 + j];
            v = s * scale;
        } else {
            v = bs[(size_t)l * 128 + (n - 512)];
        }
        biasPre[(size_t)l * NCP + n] = v;
    }
    for (int c = threadIdx.x; c < 128; c += blockDim.x) {
        float s = 0.f;
        for (int h = 0; h < 4; ++h) s += bv[(size_t)l * 512 + h * 128 + c];
        biasPost[(size_t)l * 128 + c] = 0.25f * s;
    }
}

// ---------------------------------------------------------------------------
// GEMM-pre: [M x 640] = h[M x 128] @ Bpre^T + biasPre.
// cols<512 -> q-tilde (bf16); cols>=512 -> S (fp32). 128x128 tiles.
// ---------------------------------------------------------------------------
__global__ __launch_bounds__(256) void gemm_pre(
    const unsigned short* __restrict__ Abf,   // [M][128] bf16
    const unsigned short* __restrict__ Bt,    // [640][128] bf16
    const float* __restrict__ bias,           // [640]
    unsigned short* __restrict__ Qt,          // [M][512] bf16
    float* __restrict__ Sb,                   // [M][128] fp32
    int M)
{
    __shared__ unsigned short As[128][72];
    __shared__ unsigned short Bs[128][72];

    const int tid = threadIdx.x;
    const int wave = tid >> 6, lane = tid & 63;
    const int lane16 = lane & 15, quad = lane >> 4;
    const int wr = wave >> 1, wc = wave & 1;
    const int row0 = blockIdx.y * 128;
    const int col0 = blockIdx.x * 128;

    f32x4 acc[4][4] = {};

    for (int kk = 0; kk < 128; kk += 64) {
#pragma unroll
        for (int j = 0; j < 4; ++j) {
            int c = tid + j * 256;
            int r = c >> 3, c8 = (c & 7) * 8;
            bf16x8 v = {};
            if (row0 + r < M) v = *(const bf16x8*)(Abf + (size_t)(row0 + r) * 128 + kk + c8);
            *(bf16x8*)&As[r][c8] = v;
        }
#pragma unroll
        for (int j = 0; j < 4; ++j) {
            int c = tid + j * 256;
            int r = c >> 3, c8 = (c & 7) * 8;
            *(bf16x8*)&Bs[r][c8] = *(const bf16x8*)(Bt + (size_t)(col0 + r) * 128 + kk + c8);
        }
        __syncthreads();

#pragma unroll
        for (int ks = 0; ks < 2; ++ks) {
            bf16x8 a[4], b[4];
#pragma unroll
            for (int i = 0; i < 4; ++i)
                a[i] = *(const bf16x8*)&As[wr * 64 + i * 16 + lane16][ks * 32 + quad * 8];
#pragma unroll
            for (int i = 0; i < 4; ++i)
                b[i] = *(const bf16x8*)&Bs[wc * 64 + i * 16 + lane16][ks * 32 + quad * 8];
#pragma unroll
            for (int mi = 0; mi < 4; ++mi)
#pragma unroll
                for (int ni = 0; ni < 4; ++ni)
                    acc[mi][ni] = __builtin_amdgcn_mfma_f32_16x16x32_bf16(
                        a[mi], b[ni], acc[mi][ni], 0, 0, 0);
        }
        __syncthreads();
    }

#pragma unroll
    for (int mi = 0; mi < 4; ++mi) {
        int rowb = row0 + wr * 64 + mi * 16 + quad * 4;
#pragma unroll
        for (int ni = 0; ni < 4; ++ni) {
            int col = col0 + wc * 64 + ni * 16 + lane16;
            float bv = bias[col];
#pragma unroll
            for (int r = 0; r < 4; ++r) {
                int gr = rowb + r;
                if (gr < M) {
                    float v = acc[mi][ni][r] + bv;
                    if (col < 512) Qt[(size_t)gr * 512 + col] = f2bf(v);
                    else           Sb[(size_t)gr * 128 + (col - 512)] = v;
                }
            }
        }
    }
}

// ---------------------------------------------------------------------------
// FUSED attention on raw features: wave = node; 16-lane group = edge slot
// computing all 4 head logits for its edge. Gathers ONLY h[src] (256 B/edge,
// 2.56 MB working set -> L2-resident). Outputs per-head normalized
// aggregation Agg[N][512] (bf16) = sum_e a_eh * h_src.
// ---------------------------------------------------------------------------
__global__ __launch_bounds__(256) void attn_agg(
    const unsigned short* __restrict__ Qt,   // [N][512] bf16 (scale+bqk folded)
    const unsigned short* __restrict__ Hb,   // [N][128] bf16
    const int* __restrict__ row_ptr,
    const int* __restrict__ csr_src,
    unsigned short* __restrict__ Agg,        // [N][512] bf16
    int N)
{
    __shared__ float lds_a[4][64][4];        // [wave][edge-in-chunk][head]
    __shared__ float lds_rs[4][4];
    __shared__ float lds_z[4][4];

    const int tid = threadIdx.x;
    const int wave = tid >> 6;
    const int g = (tid >> 4) & 3;            // edge-slot group / head owner
    const int l16 = tid & 15;
    const int node = blockIdx.x * 4 + wave;
    if (node >= N) return;

    // q-tilde for all 4 heads, this lane's 8 channels
    float qf[4][8];
#pragma unroll
    for (int h = 0; h < 4; ++h) {
        bf16x8 qv = *(const bf16x8*)(Qt + (size_t)node * HF + h * F + l16 * 8);
#pragma unroll
        for (int j = 0; j < 8; ++j) qf[h][j] = bf2f((unsigned short)qv[j]);
    }
    const unsigned short* Hl = Hb + (size_t)l16 * 8;

    const int beg = row_ptr[node];
    const int end = row_ptr[node + 1];

    float m = -INFINITY, z = 0.f;            // this lane's group owns head g
    float acc[4][8] = {};

    for (int cb = beg; cb < end; cb += 64) {
        const int ce = (cb + 64 < end) ? cb + 64 : end;
        const int cnt = ce - cb;

        // ---- phase A: logits (groups stride 4 over edges, unroll x2)
        int i = cb + g;
        for (; i + 4 < ce; i += 8) {
            int s0 = csr_src[i], s1 = csr_src[i + 4];
            bf16x8 h0 = *(const bf16x8*)(Hl + (size_t)s0 * F);
            bf16x8 h1 = *(const bf16x8*)(Hl + (size_t)s1 * F);
            float hf0[8], hf1[8];
#pragma unroll
            for (int j = 0; j < 8; ++j) { hf0[j] = bf2f((unsigned short)h0[j]); hf1[j] = bf2f((unsigned short)h1[j]); }
            float p0[4] = {}, p1[4] = {};
#pragma unroll
            for (int h = 0; h < 4; ++h)
#pragma unroll
                for (int j = 0; j < 8; ++j) { p0[h] += qf[h][j] * hf0[j]; p1[h] += qf[h][j] * hf1[j]; }
#pragma unroll
            for (int off = 1; off < 16; off <<= 1)
#pragma unroll
                for (int h = 0; h < 4; ++h) { p0[h] += __shfl_xor(p0[h], off, 64); p1[h] += __shfl_xor(p1[h], off, 64); }
            if (l16 < 4) {
                float v0 = l16 == 0 ? p0[0] : l16 == 1 ? p0[1] : l16 == 2 ? p0[2] : p0[3];
                float v1 = l16 == 0 ? p1[0] : l16 == 1 ? p1[1] : l16 == 2 ? p1[2] : p1[3];
                lds_a[wave][i - cb][l16] = v0;
                lds_a[wave][i + 4 - cb][l16] = v1;
            }
        }
        for (; i < ce; i += 4) {
            int s0 = csr_src[i];
            bf16x8 h0 = *(const bf16x8*)(Hl + (size_t)s0 * F);
            float hf0[8];
#pragma unroll
            for (int j = 0; j < 8; ++j) hf0[j] = bf2f((unsigned short)h0[j]);
            float p0[4] = {};
#pragma unroll
            for (int h = 0; h < 4; ++h)
#pragma unroll
                for (int j = 0; j < 8; ++j) p0[h] += qf[h][j] * hf0[j];
#pragma unroll
            for (int off = 1; off < 16; off <<= 1)
#pragma unroll
                for (int h = 0; h < 4; ++h) p0[h] += __shfl_xor(p0[h], off, 64);
            if (l16 < 4) {
                float v0 = l16 == 0 ? p0[0] : l16 == 1 ? p0[1] : l16 == 2 ? p0[2] : p0[3];
                lds_a[wave][i - cb][l16] = v0;
            }
        }

        // ---- chunk max for head g + online rescale
        float mc = -INFINITY;
        for (int t = l16; t < cnt; t += 16) mc = fmaxf(mc, lds_a[wave][t][g]);
#pragma unroll
        for (int off = 1; off < 16; off <<= 1) mc = fmaxf(mc, __shfl_xor(mc, off, 64));
        float mn = fmaxf(m, mc);
        float rs = __expf(m - mn);           // 0 on first chunk
        m = mn;
        z *= rs;
        if (l16 == 0) lds_rs[wave][g] = rs;
        float r0 = lds_rs[wave][0], r1 = lds_rs[wave][1];
        float r2 = lds_rs[wave][2], r3 = lds_rs[wave][3];
#pragma unroll
        for (int j = 0; j < 8; ++j) {
            acc[0][j] *= r0; acc[1][j] *= r1; acc[2][j] *= r2; acc[3][j] *= r3;
        }

        // ---- phase B: weights for head g
        for (int t = l16; t < cnt; t += 16) {
            float w = __expf(lds_a[wave][t][g] - m);
            z += w;
            lds_a[wave][t][g] = w;
        }

        // ---- phase C: aggregate h_src with per-head weights
        i = cb + g;
        for (; i + 4 < ce; i += 8) {
            int s0 = csr_src[i], s1 = csr_src[i + 4];
            bf16x8 h0 = *(const bf16x8*)(Hl + (size_t)s0 * F);
            bf16x8 h1 = *(const bf16x8*)(Hl + (size_t)s1 * F);
            float4 w0 = *(const float4*)&lds_a[wave][i - cb][0];
            float4 w1 = *(const float4*)&lds_a[wave][i + 4 - cb][0];
#pragma unroll
            for (int j = 0; j < 8; ++j) {
                float f0 = bf2f((unsigned short)h0[j]);
                float f1 = bf2f((unsigned short)h1[j]);
                acc[0][j] += w0.x * f0 + w1.x * f1;
                acc[1][j] += w0.y * f0 + w1.y * f1;
                acc[2][j] += w0.z * f0 + w1.z * f1;
                acc[3][j] += w0.w * f0 + w1.w * f1;
            }
        }
        for (; i < ce; i += 4) {
            int s0 = csr_src[i];
            bf16x8 h0 = *(const bf16x8*)(Hl + (size_t)s0 * F);
            float4 w0 = *(const float4*)&lds_a[wave][i - cb][0];
#pragma unroll
            for (int j = 0; j < 8; ++j) {
                float f0 = bf2f((unsigned short)h0[j]);
                acc[0][j] += w0.x * f0;
                acc[1][j] += w0.y * f0;
                acc[2][j] += w0.z * f0;
                acc[3][j] += w0.w * f0;
            }
        }
    }

    // ---- finalize: z across group, normalize, reduce across groups
#pragma unroll
    for (int off = 1; off < 16; off <<= 1) z += __shfl_xor(z, off, 64);
    if (l16 == 0) lds_z[wave][g] = z;
    float z0 = lds_z[wave][0], z1 = lds_z[wave][1];
    float z2 = lds_z[wave][2], z3 = lds_z[wave][3];
    float i0 = (z0 > 0.f) ? 1.f / z0 : 0.f;
    float i1 = (z1 > 0.f) ? 1.f / z1 : 0.f;
    float i2 = (z2 > 0.f) ? 1.f / z2 : 0.f;
    float i3 = (z3 > 0.f) ? 1.f / z3 : 0.f;
#pragma unroll
    for (int j = 0; j < 8; ++j) {
        acc[0][j] *= i0; acc[1][j] *= i1; acc[2][j] *= i2; acc[3][j] *= i3;
    }
#pragma unroll
    for (int h = 0; h < 4; ++h)
#pragma unroll
        for (int j = 0; j < 8; ++j) {
            acc[h][j] += __shfl_xor(acc[h][j], 16, 64);
            acc[h][j] += __shfl_xor(acc[h][j], 32, 64);
        }

    // group g writes head g's 256 B slice -> whole wave writes the 1 KB row
    unsigned short* op = Agg + (size_t)node * HF + g * F + l16 * 8;
    bf16x8 o;
    if (g == 0) {
#pragma unroll
        for (int j = 0; j < 8; ++j) o[j] = (short)f2bf(acc[0][j]);
    } else if (g == 1) {
#pragma unroll
        for (int j = 0; j < 8; ++j) o[j] = (short)f2bf(acc[1][j]);
    } else if (g == 2) {
#pragma unroll
        for (int j = 0; j < 8; ++j) o[j] = (short)f2bf(acc[2][j]);
    } else {
#pragma unroll
        for (int j = 0; j < 8; ++j) o[j] = (short)f2bf(acc[3][j]);
    }
    *(bf16x8*)op = o;
}

// ---------------------------------------------------------------------------
// GEMM-post: out[M x 128] = Agg[M x 512] @ Bpost^T + biasPost + S, (ReLU).
// 64x64 tiles (314 blocks), wave w covers cols w*16..w*16+15.
// ---------------------------------------------------------------------------
__global__ __launch_bounds__(256) void gemm_post(
    const unsigned short* __restrict__ Agg,   // [M][512] bf16
    const unsigned short* __restrict__ Bt,    // [128][512] bf16
    const float* __restrict__ bias,           // [128]
    const float* __restrict__ Sb,             // [M][128]
    float* __restrict__ out_f,
    unsigned short* __restrict__ out_bf,
    int relu, int M)
{
    __shared__ unsigned short As[64][72];
    __shared__ unsigned short Bs[64][72];

    const int tid = threadIdx.x;
    const int wave = tid >> 6, lane = tid & 63;
    const int lane16 = lane & 15, quad = lane >> 4;
    const int row0 = blockIdx.y * 64;
    const int col0 = blockIdx.x * 64;

    f32x4 acc[4] = {};

    for (int kk = 0; kk < 512; kk += 64) {
#pragma unroll
        for (int rep = 0; rep < 2; ++rep) {
            int c = tid + rep * 256;
            int r = c >> 3, c8 = (c & 7) * 8;
            bf16x8 v = {};
            if (row0 + r < M) v = *(const bf16x8*)(Agg + (size_t)(row0 + r) * 512 + kk + c8);
            *(bf16x8*)&As[r][c8] = v;
            *(bf16x8*)&Bs[r][c8] = *(const bf16x8*)(Bt + (size_t)(col0 + r) * 512 + kk + c8);
        }
        __syncthreads();

#pragma unroll
        for (int ks = 0; ks < 2; ++ks) {
            bf16x8 b = *(const bf16x8*)&Bs[wave * 16 + lane16][ks * 32 + quad * 8];
#pragma unroll
            for (int mt = 0; mt < 4; ++mt) {
                bf16x8 a = *(const bf16x8*)&As[mt * 16 + lane16][ks * 32 + quad * 8];
                acc[mt] = __builtin_amdgcn_mfma_f32_16x16x32_bf16(a, b, acc[mt], 0, 0, 0);
            }
        }
        __syncthreads();
    }

    const int col = col0 + wave * 16 + lane16;
    const float bcol = bias[col];
#pragma unroll
    for (int mt = 0; mt < 4; ++mt) {
#pragma unroll
        for (int r = 0; r < 4; ++r) {
            int row = row0 + mt * 16 + quad * 4 + r;
            if (row < M) {
                float v = acc[mt][r] + bcol + Sb[(size_t)row * 128 + col];
                if (relu) v = fmaxf(v, 0.f);
                if (out_f)  out_f[(size_t)row * 128 + col] = v;
                if (out_bf) out_bf[(size_t)row * 128 + col] = f2bf(v);
            }
        }
    }
}

// ---------------------------------------------------------------------------
// Launch
// ---------------------------------------------------------------------------
extern "C" void kernel_launch(void* const* d_in, const int* in_sizes, int n_in,
                              void* d_out, int out_size, void* d_ws, size_t ws_size,
                              hipStream_t stream) {
    const float* x     = (const float*)d_in[0];
    const int*   ei    = (const int*)d_in[1];
    const float* Wq    = (const float*)d_in[2];
    const float* bq    = (const float*)d_in[3];
    const float* Wk    = (const float*)d_in[4];
    const float* bk    = (const float*)d_in[5];   // cancels in softmax (exact)
    const float* Wv    = (const float*)d_in[6];
    const float* bv    = (const float*)d_in[7];
    const float* Wskip = (const float*)d_in[8];
    const float* bskip = (const float*)d_in[9];
    float* out = (float*)d_out;
    (void)bk;

    const int N = in_sizes[0] / F;       // 10000
    const int E = in_sizes[1] / 2;       // 160000
    const float scale = 0.08838834764831845f;   // 1/sqrt(128)

    const int* src = ei;
    const int* dst = ei + E;

    // Workspace layout
    char* p = (char*)d_ws;
    float* Sb       = (float*)p;               p += (size_t)N * F * sizeof(float);
    float* biasPreP = (float*)p;               p += (size_t)LAYERS * NCP * sizeof(float);
    float* biasPostP= (float*)p;               p += (size_t)LAYERS * 128 * sizeof(float);
    unsigned short* h_bf  = (unsigned short*)p; p += (size_t)N * F * sizeof(unsigned short);
    unsigned short* Qt    = (unsigned short*)p; p += (size_t)N * HF * sizeof(unsigned short);
    unsigned short* AggB  = (unsigned short*)p; p += (size_t)N * HF * sizeof(unsigned short);
    unsigned short* BpreP = (unsigned short*)p; p += (size_t)LAYERS * NCP * 128 * sizeof(unsigned short);
    unsigned short* BpostP= (unsigned short*)p; p += (size_t)LAYERS * 128 * 512 * sizeof(unsigned short);
    int* deg     = (int*)p;                    p += (size_t)N * sizeof(int);
    int* cursor  = (int*)p;                    p += (size_t)N * sizeof(int);
    int* row_ptr = (int*)p;                    p += (size_t)(N + 1) * sizeof(int);
    int* csr_src = (int*)p;

    // --- CSR build
    hipMemsetAsync(deg, 0, 2 * (size_t)N * sizeof(int), stream);  // deg + cursor
    {
        int blocks = (E + 255) / 256;
        hist_kernel<<<blocks, 256, 0, stream>>>(dst, deg, E);
        scan_kernel<<<1, 1024, 0, stream>>>(deg, row_ptr, N);
        scatter_kernel<<<blocks, 256, 0, stream>>>(src, dst, row_ptr, cursor, csr_src, E);
    }

    // --- One-time packs/converts
    convert_kernel<<<(N * F / 4 + 255) / 256, 256, 0, stream>>>(x, h_bf, N * F / 4);
    {
        dim3 g(2, 2, LAYERS * H);
        wqk_kernel<<<g, 256, 0, stream>>>(Wq, Wk, BpreP, scale);
    }
    {
        dim3 g(4, 4, LAYERS);
        pack_ws_kernel<<<g, 256, 0, stream>>>(Wskip, BpreP);
    }
    {
        dim3 g(4, 4, LAYERS * H);
        pack_bpost_kernel<<<g, 256, 0, stream>>>(Wv, BpostP);
    }
    bias_kernel<<<LAYERS, 256, 0, stream>>>(bq, Wk, bskip, bv, biasPreP, biasPostP, scale);

    const int rowBlocks128 = (N + 127) / 128;
    const int rowBlocks64  = (N + 63) / 64;
    const int attnBlocks   = (N + 3) / 4;

    for (int l = 0; l < LAYERS; ++l) {
        dim3 gridPre(NCP / 128, rowBlocks128);
        gemm_pre<<<gridPre, 256, 0, stream>>>(h_bf,
                                              BpreP + (size_t)l * NCP * 128,
                                              biasPreP + (size_t)l * NCP,
                                              Qt, Sb, N);

        attn_agg<<<attnBlocks, 256, 0, stream>>>(Qt, h_bf, row_ptr, csr_src, AggB, N);

        float* out_f = nullptr;
        unsigned short* out_bf = nullptr;
        int relu;
        if (l == LAYERS - 1) { out_f = out; relu = 0; }
        else { out_bf = h_bf; relu = 1; }

        dim3 gridPost(2, rowBlocks64);
        gemm_post<<<gridPost, 256, 0, stream>>>(AggB,
                                                BpostP + (size_t)l * 128 * 512,
                                                biasPostP + (size_t)l * 128,
                                                Sb, out_f, out_bf, relu, N);
    }
}

// Round 8
// 383.595 us; speedup vs baseline: 5.0622x; 1.0077x over previous
//
#include <hip/hip_runtime.h>
#include <math.h>

static constexpr int F  = 128;    // channels per head / input dim
static constexpr int H  = 4;      // heads
static constexpr int HF = 512;    // H*F
static constexpr int NCP = 640;   // pre-GEMM cols: q-tilde(512) | S(128)
static constexpr int LAYERS = 4;

typedef __attribute__((ext_vector_type(8))) short bf16x8;   // 8 bf16 (4 VGPRs)
typedef __attribute__((ext_vector_type(4))) float f32x4;

__device__ __forceinline__ unsigned short f2bf(float f) {
    union { float f; unsigned u; } v; v.f = f;
    unsigned r = (v.u + 0x7FFFu + ((v.u >> 16) & 1u)) >> 16;  // RNE
    return (unsigned short)r;
}
__device__ __forceinline__ float bf2f(unsigned short b) {
    union { unsigned u; float f; } v; v.u = ((unsigned)b) << 16;
    return v.f;
}

// ---------------------------------------------------------------------------
// CSR build (counting sort of edges by dst)
// ---------------------------------------------------------------------------
__global__ void hist_kernel(const int* __restrict__ dst, int* __restrict__ deg, int E) {
    int e = blockIdx.x * blockDim.x + threadIdx.x;
    if (e < E) atomicAdd(&deg[dst[e]], 1);
}

__global__ void scan_kernel(const int* __restrict__ deg, int* __restrict__ row_ptr, int n) {
    __shared__ int wsum[16];
    __shared__ int carry_s, wtot_s;
    const int tid = threadIdx.x;
    const int lane = tid & 63;
    const int wid = tid >> 6;
    if (tid == 0) { carry_s = 0; row_ptr[0] = 0; }
    __syncthreads();
    for (int base = 0; base < n; base += 1024) {
        int i = base + tid;
        int x = (i < n) ? deg[i] : 0;
#pragma unroll
        for (int off = 1; off < 64; off <<= 1) {
            int t = __shfl_up(x, off, 64);
            if (lane >= off) x += t;
        }
        if (lane == 63) wsum[wid] = x;
        __syncthreads();
        if (tid == 0) {
            int s = 0;
#pragma unroll
            for (int j = 0; j < 16; ++j) { int t = wsum[j]; wsum[j] = s; s += t; }
            wtot_s = s;
        }
        __syncthreads();
        int incl = x + wsum[wid] + carry_s;
        if (i < n) row_ptr[i + 1] = incl;
        __syncthreads();
        if (tid == 0) carry_s += wtot_s;
        __syncthreads();
    }
}

__global__ void scatter_kernel(const int* __restrict__ src, const int* __restrict__ dst,
                               const int* __restrict__ row_ptr, int* __restrict__ cursor,
                               int* __restrict__ csr_src, int E) {
    int e = blockIdx.x * blockDim.x + threadIdx.x;
    if (e < E) {
        int d = dst[e];
        int pos = atomicAdd(&cursor[d], 1);
        csr_src[row_ptr[d] + pos] = src[e];
    }
}

// ---------------------------------------------------------------------------
// Merged one-time prep: convert | wqk | pack_ws | pack_bpost | bias
// dispatched by 1-D block-index ranges.
// ---------------------------------------------------------------------------
static constexpr int NB_CONV  = 1250;   // N*F/4 / 256
static constexpr int NB_WQK   = 64;     // 2 x 2 x (L*H)
static constexpr int NB_WS    = 64;     // 4 x 4 x L
static constexpr int NB_BPOST = 256;    // 4 x 4 x (L*H)
static constexpr int NB_BIAS  = LAYERS;
static constexpr int NB_PREP  = NB_CONV + NB_WQK + NB_WS + NB_BPOST + NB_BIAS;

__global__ __launch_bounds__(256) void prep_kernel(
    const float* __restrict__ x, unsigned short* __restrict__ h_bf, int n4,
    const float* __restrict__ Wq, const float* __restrict__ Wk,
    const float* __restrict__ Wv, const float* __restrict__ Ws,
    const float* __restrict__ bq, const float* __restrict__ bs, const float* __restrict__ bv,
    unsigned short* __restrict__ Bpre, unsigned short* __restrict__ Bpost,
    float* __restrict__ biasPre, float* __restrict__ biasPost, float scale)
{
    __shared__ __attribute__((aligned(16))) float smem[64 * 33 * 2];   // 16.9 KB, reused by tasks
    const int tid = threadIdx.x;
    int b = blockIdx.x;

    if (b < NB_CONV) {
        // ---- convert x -> bf16
        int i = b * 256 + tid;
        if (i < n4) {
            float4 v = *(const float4*)(x + (size_t)i * 4);
            ushort4 o;
            o.x = f2bf(v.x); o.y = f2bf(v.y); o.z = f2bf(v.z); o.w = f2bf(v.w);
            *(ushort4*)(h_bf + (size_t)i * 4) = o;
        }
        return;
    }
    b -= NB_CONV;
    if (b < NB_WQK) {
        // ---- Wqk composite: Bpre[l][h*128+c][k] = scale * Wq[l][:,h]_k . Wk[l][:,h]_c
        float (*As)[33] = (float (*)[33])smem;            // Wk rows (c)
        float (*Bs)[33] = (float (*)[33])(smem + 64 * 33);// Wq rows (k)
        const int bx = b & 1, by = (b >> 1) & 1, lh = b >> 2;
        const int l = lh >> 2, h = lh & 3;
        const int c0 = by * 64, k0 = bx * 64;
        const float* Ab = Wk + (size_t)l * 65536 + h * 128;
        const float* Bb = Wq + (size_t)l * 65536 + h * 128;
        const int tx = tid & 15, ty = tid >> 4;
        float acc[4][4] = {};
        for (int jj = 0; jj < 128; jj += 32) {
#pragma unroll
            for (int rep = 0; rep < 2; ++rep) {
                int f = tid + rep * 256;
                int r = f >> 3, j4 = (f & 7) * 4;
                float4 a = *(const float4*)(Ab + (size_t)(c0 + r) * 512 + jj + j4);
                As[r][j4 + 0] = a.x; As[r][j4 + 1] = a.y; As[r][j4 + 2] = a.z; As[r][j4 + 3] = a.w;
                float4 bb = *(const float4*)(Bb + (size_t)(k0 + r) * 512 + jj + j4);
                Bs[r][j4 + 0] = bb.x; Bs[r][j4 + 1] = bb.y; Bs[r][j4 + 2] = bb.z; Bs[r][j4 + 3] = bb.w;
            }
            __syncthreads();
#pragma unroll
            for (int j = 0; j < 32; ++j) {
                float a0 = As[ty * 4 + 0][j], a1 = As[ty * 4 + 1][j];
                float a2 = As[ty * 4 + 2][j], a3 = As[ty * 4 + 3][j];
                float b0 = Bs[tx * 4 + 0][j], b1 = Bs[tx * 4 + 1][j];
                float b2 = Bs[tx * 4 + 2][j], b3 = Bs[tx * 4 + 3][j];
                acc[0][0] += a0 * b0; acc[0][1] += a0 * b1; acc[0][2] += a0 * b2; acc[0][3] += a0 * b3;
                acc[1][0] += a1 * b0; acc[1][1] += a1 * b1; acc[1][2] += a1 * b2; acc[1][3] += a1 * b3;
                acc[2][0] += a2 * b0; acc[2][1] += a2 * b1; acc[2][2] += a2 * b2; acc[2][3] += a2 * b3;
                acc[3][0] += a3 * b0; acc[3][1] += a3 * b1; acc[3][2] += a3 * b2; acc[3][3] += a3 * b3;
            }
            __syncthreads();
        }
#pragma unroll
        for (int i = 0; i < 4; ++i)
#pragma unroll
            for (int t = 0; t < 4; ++t) {
                int c = c0 + ty * 4 + i;
                int k = k0 + tx * 4 + t;
                Bpre[(size_t)l * NCP * 128 + (size_t)(h * 128 + c) * 128 + k] = f2bf(scale * acc[i][t]);
            }
        return;
    }
    b -= NB_WQK;
    if (b < NB_WS) {
        // ---- pack skip weights: Bpre[l][512+n][k] = Ws[l][k][n]
        unsigned short (*t)[33] = (unsigned short (*)[33])smem;
        const int bx = b & 3, by = (b >> 2) & 3, l = b >> 4;
        const int k0 = bx * 32, n0 = by * 32;
        const int cx = tid & 31, ry = tid >> 5;
#pragma unroll
        for (int rr = 0; rr < 32; rr += 8) {
            int k = k0 + ry + rr;
            t[ry + rr][cx] = f2bf(Ws[(size_t)l * 16384 + (size_t)k * 128 + n0 + cx]);
        }
        __syncthreads();
#pragma unroll
        for (int rr = 0; rr < 32; rr += 8) {
            int n = n0 + ry + rr;
            Bpre[(size_t)l * NCP * 128 + (size_t)(512 + n) * 128 + k0 + cx] = t[cx][ry + rr];
        }
        return;
    }
    b -= NB_WS;
    if (b < NB_BPOST) {
        // ---- pack post weights: Bpost[l][co][h*128+ci] = 0.25*Wv[l][ci][h*128+co]
        unsigned short (*t)[33] = (unsigned short (*)[33])smem;
        const int bx = b & 3, by = (b >> 2) & 3, lh = b >> 4;
        const int l = lh >> 2, h = lh & 3;
        const int ci0 = bx * 32, co0 = by * 32;
        const int cx = tid & 31, ry = tid >> 5;
#pragma unroll
        for (int rr = 0; rr < 32; rr += 8) {
            int ci = ci0 + ry + rr;
            t[ry + rr][cx] = f2bf(0.25f * Wv[(size_t)l * 65536 + (size_t)ci * 512 + h * 128 + co0 + cx]);
        }
        __syncthreads();
#pragma unroll
        for (int rr = 0; rr < 32; rr += 8) {
            int co = co0 + ry + rr;
            Bpost[(size_t)l * 65536 + (size_t)co * 512 + h * 128 + ci0 + cx] = t[cx][ry + rr];
        }
        return;
    }
    b -= NB_BPOST;
    {
        // ---- biases for layer l = b
        const int l = b;
        for (int n = tid; n < NCP; n += 256) {
            float v;
            if (n < 512) {
                int h = n >> 7, c = n & 127;
                float s = 0.f;
                for (int j = 0; j < 128; ++j)
                    s += bq[(size_t)l * 512 + h * 128 + j] * Wk[(size_t)l * 65536 + (size_t)c * 512 + h * 128 + j];
                v = s * scale;
            } else {
                v = bs[(size_t)l * 128 + (n - 512)];
            }
            biasPre[(size_t)l * NCP + n] = v;
        }
        for (int c = tid; c < 128; c += 256) {
            float s = 0.f;
            for (int h = 0; h < 4; ++h) s += bv[(size_t)l * 512 + h * 128 + c];
            biasPost[(size_t)l * 128 + c] = 0.25f * s;
        }
    }
}

// ---------------------------------------------------------------------------
// GEMM-pre: [M x 640] = h[M x 128] @ Bpre^T + biasPre.
// cols<512 -> q-tilde (bf16); cols>=512 -> S (fp32). 128x128 tiles.
// ---------------------------------------------------------------------------
__global__ __launch_bounds__(256) void gemm_pre(
    const unsigned short* __restrict__ Abf,   // [M][128] bf16
    const unsigned short* __restrict__ Bt,    // [640][128] bf16
    const float* __restrict__ bias,           // [640]
    unsigned short* __restrict__ Qt,          // [M][512] bf16
    float* __restrict__ Sb,                   // [M][128] fp32
    int M)
{
    __shared__ unsigned short As[128][72];
    __shared__ unsigned short Bs[128][72];

    const int tid = threadIdx.x;
    const int wave = tid >> 6, lane = tid & 63;
    const int lane16 = lane & 15, quad = lane >> 4;
    const int wr = wave >> 1, wc = wave & 1;
    const int row0 = blockIdx.y * 128;
    const int col0 = blockIdx.x * 128;

    f32x4 acc[4][4] = {};

    for (int kk = 0; kk < 128; kk += 64) {
#pragma unroll
        for (int j = 0; j < 4; ++j) {
            int c = tid + j * 256;
            int r = c >> 3, c8 = (c & 7) * 8;
            bf16x8 v = {};
            if (row0 + r < M) v = *(const bf16x8*)(Abf + (size_t)(row0 + r) * 128 + kk + c8);
            *(bf16x8*)&As[r][c8] = v;
        }
#pragma unroll
        for (int j = 0; j < 4; ++j) {
            int c = tid + j * 256;
            int r = c >> 3, c8 = (c & 7) * 8;
            *(bf16x8*)&Bs[r][c8] = *(const bf16x8*)(Bt + (size_t)(col0 + r) * 128 + kk + c8);
        }
        __syncthreads();

#pragma unroll
        for (int ks = 0; ks < 2; ++ks) {
            bf16x8 a[4], b[4];
#pragma unroll
            for (int i = 0; i < 4; ++i)
                a[i] = *(const bf16x8*)&As[wr * 64 + i * 16 + lane16][ks * 32 + quad * 8];
#pragma unroll
            for (int i = 0; i < 4; ++i)
                b[i] = *(const bf16x8*)&Bs[wc * 64 + i * 16 + lane16][ks * 32 + quad * 8];
#pragma unroll
            for (int mi = 0; mi < 4; ++mi)
#pragma unroll
                for (int ni = 0; ni < 4; ++ni)
                    acc[mi][ni] = __builtin_amdgcn_mfma_f32_16x16x32_bf16(
                        a[mi], b[ni], acc[mi][ni], 0, 0, 0);
        }
        __syncthreads();
    }

#pragma unroll
    for (int mi = 0; mi < 4; ++mi) {
        int rowb = row0 + wr * 64 + mi * 16 + quad * 4;
#pragma unroll
        for (int ni = 0; ni < 4; ++ni) {
            int col = col0 + wc * 64 + ni * 16 + lane16;
            float bv = bias[col];
#pragma unroll
            for (int r = 0; r < 4; ++r) {
                int gr = rowb + r;
                if (gr < M) {
                    float v = acc[mi][ni][r] + bv;
                    if (col < 512) Qt[(size_t)gr * 512 + col] = f2bf(v);
                    else           Sb[(size_t)gr * 128 + (col - 512)] = v;
                }
            }
        }
    }
}

// ---------------------------------------------------------------------------
// ONE-PASS flash attention aggregation: wave = node; 16-lane group g owns
// edge positions beg+g, beg+g+4, ... (stride 4) and keeps private running
// (m,z,acc) for ALL 4 heads over its subset. Per batch of 4 edges: 4
// independent gathers in flight, 16 logits, one flash update, aggregation
// straight from registers (single gather per edge, no LDS). Group partials
// merged at the end with a butterfly flash-combine.
// ---------------------------------------------------------------------------
__global__ __launch_bounds__(256) void attn_agg(
    const unsigned short* __restrict__ Qt,   // [N][512] bf16 (scale+bqk folded)
    const unsigned short* __restrict__ Hb,   // [N][128] bf16
    const int* __restrict__ row_ptr,
    const int* __restrict__ csr_src,
    unsigned short* __restrict__ Agg,        // [N][512] bf16
    int N)
{
    const int tid = threadIdx.x;
    const int wave = tid >> 6;
    const int g = (tid >> 4) & 3;
    const int l16 = tid & 15;
    const int node = blockIdx.x * 4 + wave;
    if (node >= N) return;

    const float NEG = -3e38f;   // finite sentinel: exp(NEG - finite) == 0, no NaN

    // q-tilde for all 4 heads, this lane's 8 channels (same across groups -> L1 broadcast)
    float qf[4][8];
#pragma unroll
    for (int h = 0; h < 4; ++h) {
        bf16x8 qv = *(const bf16x8*)(Qt + (size_t)node * HF + h * F + l16 * 8);
#pragma unroll
        for (int j = 0; j < 8; ++j) qf[h][j] = bf2f((unsigned short)qv[j]);
    }
    const unsigned short* Hl = Hb + (size_t)l16 * 8;

    const int beg = row_ptr[node];
    const int end = row_ptr[node + 1];

    float m[4], z[4], acc[4][8];
#pragma unroll
    for (int h = 0; h < 4; ++h) { m[h] = NEG; z[h] = 0.f; }
#pragma unroll
    for (int h = 0; h < 4; ++h)
#pragma unroll
        for (int j = 0; j < 8; ++j) acc[h][j] = 0.f;

    for (int base = beg + g; base < end; base += 16) {
        // slot 0 always valid; clamp invalid slots to a valid position
        const int i1 = base + 4, i2 = base + 8, i3 = base + 12;
        const bool v1 = i1 < end, v2 = i2 < end, v3 = i3 < end;
        int s0 = csr_src[base];
        int s1 = csr_src[v1 ? i1 : base];
        int s2 = csr_src[v2 ? i2 : base];
        int s3 = csr_src[v3 ? i3 : base];
        // 4 independent gathers in flight
        bf16x8 hb0 = *(const bf16x8*)(Hl + (size_t)s0 * F);
        bf16x8 hb1 = *(const bf16x8*)(Hl + (size_t)s1 * F);
        bf16x8 hb2 = *(const bf16x8*)(Hl + (size_t)s2 * F);
        bf16x8 hb3 = *(const bf16x8*)(Hl + (size_t)s3 * F);
        float hf[4][8];
#pragma unroll
        for (int j = 0; j < 8; ++j) {
            hf[0][j] = bf2f((unsigned short)hb0[j]);
            hf[1][j] = bf2f((unsigned short)hb1[j]);
            hf[2][j] = bf2f((unsigned short)hb2[j]);
            hf[3][j] = bf2f((unsigned short)hb3[j]);
        }
        // 16 logits (4 slots x 4 heads), partial per lane
        float p[4][4];
#pragma unroll
        for (int e = 0; e < 4; ++e)
#pragma unroll
            for (int h = 0; h < 4; ++h) {
                float t = 0.f;
#pragma unroll
                for (int j = 0; j < 8; ++j) t += qf[h][j] * hf[e][j];
                p[e][h] = t;
            }
        // reduce within 16-lane group
#pragma unroll
        for (int off = 1; off < 16; off <<= 1)
#pragma unroll
            for (int e = 0; e < 4; ++e)
#pragma unroll
                for (int h = 0; h < 4; ++h)
                    p[e][h] += __shfl_xor(p[e][h], off, 64);
        // mask invalid slots
#pragma unroll
        for (int h = 0; h < 4; ++h) {
            if (!v1) p[1][h] = NEG;
            if (!v2) p[2][h] = NEG;
            if (!v3) p[3][h] = NEG;
        }
        // flash update (one rescale per 4 edges)
#pragma unroll
        for (int h = 0; h < 4; ++h) {
            float bm = fmaxf(fmaxf(p[0][h], p[1][h]), fmaxf(p[2][h], p[3][h]));
            float mn = fmaxf(m[h], bm);
            float rs = __expf(m[h] - mn);
            float w0 = __expf(p[0][h] - mn);
            float w1 = __expf(p[1][h] - mn);
            float w2 = __expf(p[2][h] - mn);
            float w3 = __expf(p[3][h] - mn);
            z[h] = z[h] * rs + (w0 + w1) + (w2 + w3);
#pragma unroll
            for (int j = 0; j < 8; ++j)
                acc[h][j] = acc[h][j] * rs
                          + w0 * hf[0][j] + w1 * hf[1][j]
                          + w2 * hf[2][j] + w3 * hf[3][j];
            m[h] = mn;
        }
    }

    // merge group partials: butterfly flash-combine across groups (xor 16, 32)
#pragma unroll
    for (int off = 16; off <= 32; off <<= 1) {
#pragma unroll
        for (int h = 0; h < 4; ++h) {
            float om = __shfl_xor(m[h], off, 64);
            float oz = __shfl_xor(z[h], off, 64);
            float M = fmaxf(m[h], om);
            float a = __expf(m[h] - M);
            float b = __expf(om - M);
            z[h] = z[h] * a + oz * b;
#pragma unroll
            for (int j = 0; j < 8; ++j) {
                float oa = __shfl_xor(acc[h][j], off, 64);
                acc[h][j] = acc[h][j] * a + oa * b;
            }
            m[h] = M;
        }
    }

    // normalize + write: group g writes head g's 256 B slice
    float i0 = (z[0] > 0.f) ? 1.f / z[0] : 0.f;
    float i1 = (z[1] > 0.f) ? 1.f / z[1] : 0.f;
    float i2 = (z[2] > 0.f) ? 1.f / z[2] : 0.f;
    float i3 = (z[3] > 0.f) ? 1.f / z[3] : 0.f;
    bf16x8 o;
    if (g == 0) {
#pragma unroll
        for (int j = 0; j < 8; ++j) o[j] = (short)f2bf(acc[0][j] * i0);
    } else if (g == 1) {
#pragma unroll
        for (int j = 0; j < 8; ++j) o[j] = (short)f2bf(acc[1][j] * i1);
    } else if (g == 2) {
#pragma unroll
        for (int j = 0; j < 8; ++j) o[j] = (short)f2bf(acc[2][j] * i2);
    } else {
#pragma unroll
        for (int j = 0; j < 8; ++j) o[j] = (short)f2bf(acc[3][j] * i3);
    }
    *(bf16x8*)(Agg + (size_t)node * HF + g * F + l16 * 8) = o;
}

// ---------------------------------------------------------------------------
// GEMM-post: out[M x 128] = Agg[M x 512] @ Bpost^T + biasPost + S, (ReLU).
// ---------------------------------------------------------------------------
__global__ __launch_bounds__(256) void gemm_post(
    const unsigned short* __restrict__ Agg,   // [M][512] bf16
    const unsigned short* __restrict__ Bt,    // [128][512] bf16
    const float* __restrict__ bias,           // [128]
    const float* __restrict__ Sb,             // [M][128]
    float* __restrict__ out_f,
    unsigned short* __restrict__ out_bf,
    int relu, int M)
{
    __shared__ unsigned short As[64][72];
    __shared__ unsigned short Bs[64][72];

    const int tid = threadIdx.x;
    const int wave = tid >> 6, lane = tid & 63;
    const int lane16 = lane & 15, quad = lane >> 4;
    const int row0 = blockIdx.y * 64;
    const int col0 = blockIdx.x * 64;

    f32x4 acc[4] = {};

    for (int kk = 0; kk < 512; kk += 64) {
#pragma unroll
        for (int rep = 0; rep < 2; ++rep) {
            int c = tid + rep * 256;
            int r = c >> 3, c8 = (c & 7) * 8;
            bf16x8 v = {};
            if (row0 + r < M) v = *(const bf16x8*)(Agg + (size_t)(row0 + r) * 512 + kk + c8);
            *(bf16x8*)&As[r][c8] = v;
            *(bf16x8*)&Bs[r][c8] = *(const bf16x8*)(Bt + (size_t)(col0 + r) * 512 + kk + c8);
        }
        __syncthreads();

#pragma unroll
        for (int ks = 0; ks < 2; ++ks) {
            bf16x8 b = *(const bf16x8*)&Bs[wave * 16 + lane16][ks * 32 + quad * 8];
#pragma unroll
            for (int mt = 0; mt < 4; ++mt) {
                bf16x8 a = *(const bf16x8*)&As[mt * 16 + lane16][ks * 32 + quad * 8];
                acc[mt] = __builtin_amdgcn_mfma_f32_16x16x32_bf16(a, b, acc[mt], 0, 0, 0);
            }
        }
        __syncthreads();
    }

    const int col = col0 + wave * 16 + lane16;
    const float bcol = bias[col];
#pragma unroll
    for (int mt = 0; mt < 4; ++mt) {
#pragma unroll
        for (int r = 0; r < 4; ++r) {
            int row = row0 + mt * 16 + quad * 4 + r;
            if (row < M) {
                float v = acc[mt][r] + bcol + Sb[(size_t)row * 128 + col];
                if (relu) v = fmaxf(v, 0.f);
                if (out_f)  out_f[(size_t)row * 128 + col] = v;
                if (out_bf) out_bf[(size_t)row * 128 + col] = f2bf(v);
            }
        }
    }
}

// ---------------------------------------------------------------------------
// Launch
// ---------------------------------------------------------------------------
extern "C" void kernel_launch(void* const* d_in, const int* in_sizes, int n_in,
                              void* d_out, int out_size, void* d_ws, size_t ws_size,
                              hipStream_t stream) {
    const float* x     = (const float*)d_in[0];
    const int*   ei    = (const int*)d_in[1];
    const float* Wq    = (const float*)d_in[2];
    const float* bq    = (const float*)d_in[3];
    const float* Wk    = (const float*)d_in[4];
    const float* bk    = (const float*)d_in[5];   // cancels in softmax (exact)
    const float* Wv    = (const float*)d_in[6];
    const float* bv    = (const float*)d_in[7];
    const float* Wskip = (const float*)d_in[8];
    const float* bskip = (const float*)d_in[9];
    float* out = (float*)d_out;
    (void)bk;

    const int N = in_sizes[0] / F;       // 10000
    const int E = in_sizes[1] / 2;       // 160000
    const float scale = 0.08838834764831845f;   // 1/sqrt(128)

    const int* src = ei;
    const int* dst = ei + E;

    // Workspace layout
    char* p = (char*)d_ws;
    float* Sb       = (float*)p;               p += (size_t)N * F * sizeof(float);
    float* biasPreP = (float*)p;               p += (size_t)LAYERS * NCP * sizeof(float);
    float* biasPostP= (float*)p;               p += (size_t)LAYERS * 128 * sizeof(float);
    unsigned short* h_bf  = (unsigned short*)p; p += (size_t)N * F * sizeof(unsigned short);
    unsigned short* Qt    = (unsigned short*)p; p += (size_t)N * HF * sizeof(unsigned short);
    unsigned short* AggB  = (unsigned short*)p; p += (size_t)N * HF * sizeof(unsigned short);
    unsigned short* BpreP = (unsigned short*)p; p += (size_t)LAYERS * NCP * 128 * sizeof(unsigned short);
    unsigned short* BpostP= (unsigned short*)p; p += (size_t)LAYERS * 128 * 512 * sizeof(unsigned short);
    int* deg     = (int*)p;                    p += (size_t)N * sizeof(int);
    int* cursor  = (int*)p;                    p += (size_t)N * sizeof(int);
    int* row_ptr = (int*)p;                    p += (size_t)(N + 1) * sizeof(int);
    int* csr_src = (int*)p;

    // --- CSR build
    hipMemsetAsync(deg, 0, 2 * (size_t)N * sizeof(int), stream);  // deg + cursor
    {
        int blocks = (E + 255) / 256;
        hist_kernel<<<blocks, 256, 0, stream>>>(dst, deg, E);
        scan_kernel<<<1, 1024, 0, stream>>>(deg, row_ptr, N);
        scatter_kernel<<<blocks, 256, 0, stream>>>(src, dst, row_ptr, cursor, csr_src, E);
    }

    // --- One-time prep (merged): convert | wqk | pack_ws | pack_bpost | bias
    prep_kernel<<<NB_PREP, 256, 0, stream>>>(x, h_bf, N * F / 4,
                                             Wq, Wk, Wv, Wskip,
                                             bq, bskip, bv,
                                             BpreP, BpostP, biasPreP, biasPostP, scale);

    const int rowBlocks128 = (N + 127) / 128;
    const int rowBlocks64  = (N + 63) / 64;
    const int attnBlocks   = (N + 3) / 4;

    for (int l = 0; l < LAYERS; ++l) {
        dim3 gridPre(NCP / 128, rowBlocks128);
        gemm_pre<<<gridPre, 256, 0, stream>>>(h_bf,
                                              BpreP + (size_t)l * NCP * 128,
                                              biasPreP + (size_t)l * NCP,
                                              Qt, Sb, N);

        attn_agg<<<attnBlocks, 256, 0, stream>>>(Qt, h_bf, row_ptr, csr_src, AggB, N);

        float* out_f = nullptr;
        unsigned short* out_bf = nullptr;
        int relu;
        if (l == LAYERS - 1) { out_f = out; relu = 0; }
        else { out_bf = h_bf; relu = 1; }

        dim3 gridPost(2, rowBlocks64);
        gemm_post<<<gridPost, 256, 0, stream>>>(AggB,
                                                BpostP + (size_t)l * 128 * 512,
                                                biasPostP + (size_t)l * 128,
                                                Sb, out_f, out_bf, relu, N);
    }
}